// Round 4
// baseline (371.648 us; speedup 1.0000x reference)
//
#include <hip/hip_runtime.h>
#include <stddef.h>

#define N_NODES 10000
#define N_EDGES 160000
#define DIM     512
#define RBLKS   157   // ceil(10000/64)

typedef short bf16x8 __attribute__((ext_vector_type(8)));
typedef float f32x4  __attribute__((ext_vector_type(4)));

__device__ inline unsigned short bf16_rne(float f) {
    unsigned u = __builtin_bit_cast(unsigned, f);
    u += 0x7FFF + ((u >> 16) & 1);
    return (unsigned short)(u >> 16);
}
__device__ inline float bf16_to_f32(unsigned short h) {
    unsigned u = ((unsigned)h) << 16;
    return __builtin_bit_cast(float, u);
}

__device__ inline void gld_lds16(const void* g, void* lds) {
    __builtin_amdgcn_global_load_lds(
        (const __attribute__((address_space(1))) void*)g,
        (__attribute__((address_space(3))) void*)lds, 16, 0, 0);
}

// ---------------- graph preprocessing (unchanged, verified) ----------------

__global__ void zero_int_kernel(int* __restrict__ p, int n) {
    int i = blockIdx.x * blockDim.x + threadIdx.x;
    if (i < n) p[i] = 0;
}

__global__ void count_deg_kernel(const int* __restrict__ ei, int* __restrict__ deg, int E) {
    int e = blockIdx.x * blockDim.x + threadIdx.x;
    if (e < E) atomicAdd(&deg[ei[E + e]], 1);
}

__global__ void dis_kernel(const int* __restrict__ deg, float* __restrict__ dis, int n) {
    int i = blockIdx.x * blockDim.x + threadIdx.x;
    if (i < n) dis[i] = rsqrtf((float)(deg[i] + 1));
}

__global__ void scan_kernel(const int* __restrict__ deg, int* __restrict__ row_off, int n) {
    __shared__ int sm[1024];
    __shared__ int carry_s;
    if (threadIdx.x == 0) carry_s = 0;
    __syncthreads();
    for (int base = 0; base < n; base += 1024) {
        int i = base + (int)threadIdx.x;
        int v = (i < n) ? deg[i] : 0;
        sm[threadIdx.x] = v;
        __syncthreads();
        for (int off = 1; off < 1024; off <<= 1) {
            int t = (threadIdx.x >= (unsigned)off) ? sm[threadIdx.x - off] : 0;
            __syncthreads();
            sm[threadIdx.x] += t;
            __syncthreads();
        }
        int carry = carry_s;
        if (i < n) row_off[i + 1] = sm[threadIdx.x] + carry;
        __syncthreads();
        if (threadIdx.x == 1023) carry_s = carry + sm[1023];
        __syncthreads();
    }
    if (threadIdx.x == 0) row_off[0] = 0;
}

__global__ void scatter_kernel(const int* __restrict__ ei, const float* __restrict__ dis,
                               const int* __restrict__ row_off, int* __restrict__ cursor,
                               int* __restrict__ csr_src, float* __restrict__ csr_norm, int E) {
    int e = blockIdx.x * blockDim.x + threadIdx.x;
    if (e >= E) return;
    int s = ei[e];
    int d = ei[E + e];
    int slot = row_off[d] + atomicAdd(&cursor[d], 1);
    csr_src[slot]  = s;
    csr_norm[slot] = dis[s] * dis[d];
}

// ---------------- packing ----------------
// Tile layout (shorts): [blk][kt 16][arr 2(hi/lo)][idx 64][k 32], tile = 4096 shorts.
// XOR swizzle baked in: k-group slot kq stored at (kq ^ ((idx>>1)&3)).

__global__ __launch_bounds__(256) void pack_weight_kernel(const float* __restrict__ W,
                                                          short* __restrict__ WT) {
    int id = blockIdx.x * 256 + threadIdx.x;   // 32768
    int n  = id & 511;                         // coalesced over n
    int kc = id >> 9;                          // k-chunk of 8, 0..63
    int colblk = n >> 6, col = n & 63;
    int kt = kc >> 2, kq = kc & 3;
    short hi[8], lo[8];
#pragma unroll
    for (int j = 0; j < 8; ++j) {
        float v = W[(size_t)(kc * 8 + j) * 512 + n];
        unsigned short h = bf16_rne(v);
        hi[j] = (short)h;
        lo[j] = (short)bf16_rne(v - bf16_to_f32(h));
    }
    size_t base = (size_t)(colblk * 16 + kt) * 4096 + col * 32 + ((kq ^ ((col >> 1) & 3)) << 3);
    *(int4*)(WT + base)        = *(const int4*)hi;
    *(int4*)(WT + base + 2048) = *(const int4*)lo;
}

// pack A[M,512] f32 -> P0 (plain), and if DUAL also P1 (relu'd)
template<bool DUAL>
__global__ __launch_bounds__(256) void pack_a_kernel(const float* __restrict__ A,
                                                     short* __restrict__ P0,
                                                     short* __restrict__ P1, int M) {
    const int kt = blockIdx.x;         // 0..15
    const int rb = blockIdx.y;         // 0..RBLKS-1
    const int t  = threadIdx.x;
    const int r  = t >> 2;             // 0..63
    const int kq = t & 3;
    const int row = rb * 64 + r;
    float v[8] = {};
    if (row < M) {
        float4 a = *(const float4*)(A + (size_t)row * 512 + kt * 32 + kq * 8);
        float4 b = *(const float4*)(A + (size_t)row * 512 + kt * 32 + kq * 8 + 4);
        v[0]=a.x; v[1]=a.y; v[2]=a.z; v[3]=a.w; v[4]=b.x; v[5]=b.y; v[6]=b.z; v[7]=b.w;
    }
    size_t base = (size_t)(rb * 16 + kt) * 4096 + r * 32 + ((kq ^ ((r >> 1) & 3)) << 3);
    short hi[8], lo[8];
#pragma unroll
    for (int j = 0; j < 8; ++j) {
        unsigned short h = bf16_rne(v[j]);
        hi[j] = (short)h;
        lo[j] = (short)bf16_rne(v[j] - bf16_to_f32(h));
    }
    *(int4*)(P0 + base)        = *(const int4*)hi;
    *(int4*)(P0 + base + 2048) = *(const int4*)lo;
    if (DUAL) {
#pragma unroll
        for (int j = 0; j < 8; ++j) {
            float rv = fmaxf(v[j], 0.f);
            unsigned short h = bf16_rne(rv);
            hi[j] = (short)h;
            lo[j] = (short)bf16_rne(rv - bf16_to_f32(h));
        }
        *(int4*)(P1 + base)        = *(const int4*)hi;
        *(int4*)(P1 + base + 2048) = *(const int4*)lo;
    }
}

// ---------------- 1-wave 64x64 MFMA GEMM, glds double-buffer, counted vmcnt ----------------
// EPI 0: C = f32 (+bias), EPI 1: C packed bf16 hi/lo tile layout (+bias, relu)

template<int EPI>
__global__ __launch_bounds__(64, 2) void mfma_gemm64_kernel(
    const short* __restrict__ Apk, const short* __restrict__ Wpk,
    const float* __restrict__ bias,
    float* __restrict__ Cf, short* __restrict__ Cpk, int M)
{
    __shared__ short As[2][4096];
    __shared__ short Bs[2][4096];

    const int bid = blockIdx.x;            // 0..1255 (=8*157)
    const int lin = (bid & 7) * RBLKS + (bid >> 3);
    const int rowblk = lin >> 3;
    const int colblk = lin & 7;

    const int lane = threadIdx.x;
    const int l15 = lane & 15;
    const int kg  = lane >> 4;
    const int kso = ((kg ^ ((l15 >> 1) & 3)) << 3);   // swizzled k-offset (lane-const)

    const short* Abase = Apk + (size_t)rowblk * 16 * 4096;
    const short* Bbase = Wpk + (size_t)colblk * 16 * 4096;

    f32x4 acc[4][4];
#pragma unroll
    for (int i = 0; i < 4; ++i)
#pragma unroll
        for (int j = 0; j < 4; ++j) acc[i][j] = (f32x4){0.f, 0.f, 0.f, 0.f};

    auto stage = [&](int buf, int kt) {
        const char* as = (const char*)(Abase + (size_t)kt * 4096);
        const char* bs = (const char*)(Bbase + (size_t)kt * 4096);
        char* ad = (char*)&As[buf][0];
        char* bd = (char*)&Bs[buf][0];
#pragma unroll
        for (int ii = 0; ii < 8; ++ii) {
            gld_lds16(as + ii * 1024 + lane * 16, ad + ii * 1024);
            gld_lds16(bs + ii * 1024 + lane * 16, bd + ii * 1024);
        }
    };

    stage(0, 0);

#pragma unroll
    for (int kt = 0; kt < 16; ++kt) {
        const int buf = kt & 1;
        if (kt < 15) {
            stage(buf ^ 1, kt + 1);
            asm volatile("s_waitcnt vmcnt(16)" ::: "memory");
        } else {
            asm volatile("s_waitcnt vmcnt(0)" ::: "memory");
        }
        __builtin_amdgcn_sched_barrier(0);

        bf16x8 af[4][2], bf[4][2];
#pragma unroll
        for (int m = 0; m < 4; ++m) {
            int ro = (m * 16 + l15) * 32 + kso;
            af[m][0] = *(const bf16x8*)&As[buf][ro];
            af[m][1] = *(const bf16x8*)&As[buf][2048 + ro];
        }
#pragma unroll
        for (int n = 0; n < 4; ++n) {
            int co = (n * 16 + l15) * 32 + kso;
            bf[n][0] = *(const bf16x8*)&Bs[buf][co];
            bf[n][1] = *(const bf16x8*)&Bs[buf][2048 + co];
        }
#pragma unroll
        for (int m = 0; m < 4; ++m)
#pragma unroll
            for (int n = 0; n < 4; ++n) {
                acc[m][n] = __builtin_amdgcn_mfma_f32_16x16x32_bf16(af[m][0], bf[n][0], acc[m][n], 0, 0, 0);
                acc[m][n] = __builtin_amdgcn_mfma_f32_16x16x32_bf16(af[m][0], bf[n][1], acc[m][n], 0, 0, 0);
                acc[m][n] = __builtin_amdgcn_mfma_f32_16x16x32_bf16(af[m][1], bf[n][0], acc[m][n], 0, 0, 0);
            }
    }

    if (EPI == 0) {
#pragma unroll
        for (int n = 0; n < 4; ++n) {
            int c = n * 16 + l15;
            float bv = bias[colblk * 64 + c];
#pragma unroll
            for (int m = 0; m < 4; ++m) {
                int r0 = rowblk * 64 + m * 16 + kg * 4;
#pragma unroll
                for (int j = 0; j < 4; ++j) {
                    int row = r0 + j;
                    if (row < M)
                        Cf[(size_t)row * 512 + colblk * 64 + c] = acc[m][n][j] + bv;
                }
            }
        }
    } else {
#pragma unroll
        for (int n = 0; n < 4; ++n) {
            int c   = n * 16 + l15;          // 0..63
            int k_g = colblk * 64 + c;       // global k of next GEMM
            int kt_n = k_g >> 5, kk = k_g & 31, kgn = kk >> 3, kj = kk & 7;
            float bv = bias[k_g];
#pragma unroll
            for (int m = 0; m < 4; ++m) {
#pragma unroll
                for (int j = 0; j < 4; ++j) {
                    int rl  = m * 16 + kg * 4 + j;        // row within tile
                    int row = rowblk * 64 + rl;
                    float v = (row < M) ? fmaxf(acc[m][n][j] + bv, 0.f) : 0.f;
                    unsigned short h = bf16_rne(v);
                    unsigned short l = bf16_rne(v - bf16_to_f32(h));
                    size_t dst = (size_t)(rowblk * 16 + kt_n) * 4096 + rl * 32
                               + ((kgn ^ ((rl >> 1) & 3)) << 3) + kj;
                    Cpk[dst]        = (short)h;
                    Cpk[dst + 2048] = (short)l;
                }
            }
        }
    }
}

// ---------------- panel-tiled aggregation ----------------
// out[i, p*64+f] = sum_{e: dst=i} H[src_e, p*64+f]*norm_e + H[i, p*64+f]*dis[i]^2
// 8 panels of 64 floats; per-panel gather set = 2.56 MB (L2-resident per XCD).
// Block = 256 threads = 4 waves; each wave owns one node (64 lanes = 64 feats).
// Grid panel-major so co-resident blocks share one panel.

#define AGG_PANELS 8
#define AGG_NB     2500   // 10000 nodes / 4 per block

__global__ __launch_bounds__(256) void aggregate_panel_kernel(
    const float* __restrict__ H,
    const float* __restrict__ dis,
    const int* __restrict__ row_off,
    const int* __restrict__ csr_src,
    const float* __restrict__ csr_norm,
    float* __restrict__ out)
{
    const int bid   = blockIdx.x;
    const int panel = bid / AGG_NB;          // 0..7
    const int nb    = bid - panel * AGG_NB;  // 0..2499
    const int node  = nb * 4 + (threadIdx.x >> 6);
    const int f     = panel * 64 + (threadIdx.x & 63);

    const int start = row_off[node];
    const int end   = row_off[node + 1];
    const float dn  = dis[node];

    float a = H[(size_t)node * DIM + f] * (dn * dn);

    int e = start;
    for (; e + 1 < end; e += 2) {           // 2-deep index prefetch
        int s0 = csr_src[e];
        int s1 = csr_src[e + 1];
        float w0 = csr_norm[e];
        float w1 = csr_norm[e + 1];
        float h0 = H[(size_t)s0 * DIM + f];
        float h1 = H[(size_t)s1 * DIM + f];
        a += h0 * w0 + h1 * w1;
    }
    if (e < end) {
        a += H[(size_t)csr_src[e] * DIM + f] * csr_norm[e];
    }
    out[(size_t)node * DIM + f] = a;
}

// ---------------- launch ----------------

extern "C" void kernel_launch(void* const* d_in, const int* in_sizes, int n_in,
                              void* d_out, int out_size, void* d_ws, size_t ws_size,
                              hipStream_t stream) {
    const float* x   = (const float*)d_in[0];
    const int*   ei  = (const int*)d_in[1];
    const float* W1  = (const float*)d_in[2];
    const float* b1  = (const float*)d_in[3];
    const float* W2  = (const float*)d_in[4];
    const float* b2  = (const float*)d_in[5];
    const float* Wp1 = (const float*)d_in[6];
    const float* bp1 = (const float*)d_in[7];
    const float* Wp2 = (const float*)d_in[8];
    const float* bp2 = (const float*)d_in[9];

    float* out  = (float*)d_out;
    float* z    = out + (size_t)N_NODES * DIM;
    float* proj = z   + (size_t)N_NODES * DIM;

    char* ws = (char*)d_ws;
    size_t off = 0;
    auto walloc = [&](size_t bytes) -> void* {
        void* p = ws + off;
        off = (off + bytes + 255) & ~(size_t)255;
        return p;
    };
    const size_t PK_SHORTS = (size_t)RBLKS * 16 * 4096;
    float* H    = (float*)walloc((size_t)N_NODES * DIM * sizeof(float));
    short* APK0 = (short*)walloc(PK_SHORTS * sizeof(short));
    short* ZPKp = (short*)walloc(PK_SHORTS * sizeof(short));
    short* ZPKr = (short*)walloc(PK_SHORTS * sizeof(short));
    short* WT1  = (short*)walloc((size_t)8 * 16 * 4096 * sizeof(short));
    short* WT2  = (short*)walloc((size_t)8 * 16 * 4096 * sizeof(short));
    short* WTp1 = (short*)walloc((size_t)8 * 16 * 4096 * sizeof(short));
    short* WTp2 = (short*)walloc((size_t)8 * 16 * 4096 * sizeof(short));
    int*   deg      = (int*)  walloc(N_NODES * sizeof(int));
    int*   cursor   = (int*)  walloc(N_NODES * sizeof(int));
    int*   row_off  = (int*)  walloc((N_NODES + 1) * sizeof(int));
    float* dis      = (float*)walloc(N_NODES * sizeof(float));
    int*   csr_src  = (int*)  walloc(N_EDGES * sizeof(int));
    float* csr_norm = (float*)walloc(N_EDGES * sizeof(float));

    const dim3 blk(256);
    const dim3 gN((N_NODES + 255) / 256);
    const dim3 gE((N_EDGES + 255) / 256);
    const dim3 pk_grid(16, RBLKS);
    const dim3 gemm_grid(8 * RBLKS);
    const dim3 agg_grid(AGG_PANELS * AGG_NB);
    const dim3 wave(64);

    pack_weight_kernel<<<128, blk, 0, stream>>>(W1,  WT1);
    pack_weight_kernel<<<128, blk, 0, stream>>>(W2,  WT2);
    pack_weight_kernel<<<128, blk, 0, stream>>>(Wp1, WTp1);
    pack_weight_kernel<<<128, blk, 0, stream>>>(Wp2, WTp2);
    pack_a_kernel<false><<<pk_grid, blk, 0, stream>>>(x, APK0, nullptr, N_NODES);

    zero_int_kernel<<<gN, blk, 0, stream>>>(deg, N_NODES);
    zero_int_kernel<<<gN, blk, 0, stream>>>(cursor, N_NODES);
    count_deg_kernel<<<gE, blk, 0, stream>>>(ei, deg, N_EDGES);
    dis_kernel<<<gN, blk, 0, stream>>>(deg, dis, N_NODES);
    scan_kernel<<<1, 1024, 0, stream>>>(deg, row_off, N_NODES);
    scatter_kernel<<<gE, blk, 0, stream>>>(ei, dis, row_off, cursor, csr_src, csr_norm, N_EDGES);

    // z = aggregate(x @ W1 + b1)
    mfma_gemm64_kernel<0><<<gemm_grid, wave, 0, stream>>>(APK0, WT1, b1, H, nullptr, N_NODES);
    aggregate_panel_kernel<<<agg_grid, blk, 0, stream>>>(H, dis, row_off, csr_src, csr_norm, z);

    // pack z (plain + relu)
    pack_a_kernel<true><<<pk_grid, blk, 0, stream>>>(z, ZPKp, ZPKr, N_NODES);

    // out = aggregate(relu(z) @ W2 + b2)
    mfma_gemm64_kernel<0><<<gemm_grid, wave, 0, stream>>>(ZPKr, WT2, b2, H, nullptr, N_NODES);
    aggregate_panel_kernel<<<agg_grid, blk, 0, stream>>>(H, dis, row_off, csr_src, csr_norm, out);

    // P1 = relu(z @ Wp1 + bp1), written packed; proj = P1 @ Wp2 + bp2
    mfma_gemm64_kernel<1><<<gemm_grid, wave, 0, stream>>>(ZPKp, WTp1, bp1, nullptr, APK0, N_NODES);
    mfma_gemm64_kernel<0><<<gemm_grid, wave, 0, stream>>>(APK0, WTp2, bp2, proj, nullptr, N_NODES);
}

// Round 5
// 283.697 us; speedup vs baseline: 1.3100x; 1.3100x over previous
//
#include <hip/hip_runtime.h>
#include <stddef.h>

#define N_NODES 10000
#define N_EDGES 160000
#define DIM     512
#define RBLKS   157   // ceil(10000/64)

typedef short bf16x8 __attribute__((ext_vector_type(8)));
typedef float f32x4  __attribute__((ext_vector_type(4)));

__device__ inline unsigned short bf16_rne(float f) {
    unsigned u = __builtin_bit_cast(unsigned, f);
    u += 0x7FFF + ((u >> 16) & 1);
    return (unsigned short)(u >> 16);
}
__device__ inline float bf16_to_f32(unsigned short h) {
    unsigned u = ((unsigned)h) << 16;
    return __builtin_bit_cast(float, u);
}

__device__ inline void gld_lds16(const void* g, void* lds) {
    __builtin_amdgcn_global_load_lds(
        (const __attribute__((address_space(1))) void*)g,
        (__attribute__((address_space(3))) void*)lds, 16, 0, 0);
}

// ---------------- graph preprocessing (unchanged, verified) ----------------

__global__ void zero_int_kernel(int* __restrict__ p, int n) {
    int i = blockIdx.x * blockDim.x + threadIdx.x;
    if (i < n) p[i] = 0;
}

__global__ void count_deg_kernel(const int* __restrict__ ei, int* __restrict__ deg, int E) {
    int e = blockIdx.x * blockDim.x + threadIdx.x;
    if (e < E) atomicAdd(&deg[ei[E + e]], 1);
}

__global__ void dis_kernel(const int* __restrict__ deg, float* __restrict__ dis, int n) {
    int i = blockIdx.x * blockDim.x + threadIdx.x;
    if (i < n) dis[i] = rsqrtf((float)(deg[i] + 1));
}

__global__ void scan_kernel(const int* __restrict__ deg, int* __restrict__ row_off, int n) {
    __shared__ int sm[1024];
    __shared__ int carry_s;
    if (threadIdx.x == 0) carry_s = 0;
    __syncthreads();
    for (int base = 0; base < n; base += 1024) {
        int i = base + (int)threadIdx.x;
        int v = (i < n) ? deg[i] : 0;
        sm[threadIdx.x] = v;
        __syncthreads();
        for (int off = 1; off < 1024; off <<= 1) {
            int t = (threadIdx.x >= (unsigned)off) ? sm[threadIdx.x - off] : 0;
            __syncthreads();
            sm[threadIdx.x] += t;
            __syncthreads();
        }
        int carry = carry_s;
        if (i < n) row_off[i + 1] = sm[threadIdx.x] + carry;
        __syncthreads();
        if (threadIdx.x == 1023) carry_s = carry + sm[1023];
        __syncthreads();
    }
    if (threadIdx.x == 0) row_off[0] = 0;
}

__global__ void scatter_kernel(const int* __restrict__ ei, const float* __restrict__ dis,
                               const int* __restrict__ row_off, int* __restrict__ cursor,
                               int* __restrict__ csr_src, float* __restrict__ csr_norm, int E) {
    int e = blockIdx.x * blockDim.x + threadIdx.x;
    if (e >= E) return;
    int s = ei[e];
    int d = ei[E + e];
    int slot = row_off[d] + atomicAdd(&cursor[d], 1);
    csr_src[slot]  = s;
    csr_norm[slot] = dis[s] * dis[d];
}

// ---------------- packing ----------------
// Tile layout (shorts): [blk][kt 16][arr 2(hi/lo)][idx 64][k 32], tile = 4096 shorts.
// XOR swizzle baked in: k-group slot kq stored at (kq ^ ((idx>>1)&3)).

__global__ __launch_bounds__(256) void pack_weight_kernel(const float* __restrict__ W,
                                                          short* __restrict__ WT) {
    int id = blockIdx.x * 256 + threadIdx.x;   // 32768
    int n  = id & 511;                         // coalesced over n
    int kc = id >> 9;                          // k-chunk of 8, 0..63
    int colblk = n >> 6, col = n & 63;
    int kt = kc >> 2, kq = kc & 3;
    short hi[8], lo[8];
#pragma unroll
    for (int j = 0; j < 8; ++j) {
        float v = W[(size_t)(kc * 8 + j) * 512 + n];
        unsigned short h = bf16_rne(v);
        hi[j] = (short)h;
        lo[j] = (short)bf16_rne(v - bf16_to_f32(h));
    }
    size_t base = (size_t)(colblk * 16 + kt) * 4096 + col * 32 + ((kq ^ ((col >> 1) & 3)) << 3);
    *(int4*)(WT + base)        = *(const int4*)hi;
    *(int4*)(WT + base + 2048) = *(const int4*)lo;
}

// pack A[M,512] f32 -> P0 (plain), and if DUAL also P1 (relu'd)
template<bool DUAL>
__global__ __launch_bounds__(256) void pack_a_kernel(const float* __restrict__ A,
                                                     short* __restrict__ P0,
                                                     short* __restrict__ P1, int M) {
    const int kt = blockIdx.x;         // 0..15
    const int rb = blockIdx.y;         // 0..RBLKS-1
    const int t  = threadIdx.x;
    const int r  = t >> 2;             // 0..63
    const int kq = t & 3;
    const int row = rb * 64 + r;
    float v[8] = {};
    if (row < M) {
        float4 a = *(const float4*)(A + (size_t)row * 512 + kt * 32 + kq * 8);
        float4 b = *(const float4*)(A + (size_t)row * 512 + kt * 32 + kq * 8 + 4);
        v[0]=a.x; v[1]=a.y; v[2]=a.z; v[3]=a.w; v[4]=b.x; v[5]=b.y; v[6]=b.z; v[7]=b.w;
    }
    size_t base = (size_t)(rb * 16 + kt) * 4096 + r * 32 + ((kq ^ ((r >> 1) & 3)) << 3);
    short hi[8], lo[8];
#pragma unroll
    for (int j = 0; j < 8; ++j) {
        unsigned short h = bf16_rne(v[j]);
        hi[j] = (short)h;
        lo[j] = (short)bf16_rne(v[j] - bf16_to_f32(h));
    }
    *(int4*)(P0 + base)        = *(const int4*)hi;
    *(int4*)(P0 + base + 2048) = *(const int4*)lo;
    if (DUAL) {
#pragma unroll
        for (int j = 0; j < 8; ++j) {
            float rv = fmaxf(v[j], 0.f);
            unsigned short h = bf16_rne(rv);
            hi[j] = (short)h;
            lo[j] = (short)bf16_rne(rv - bf16_to_f32(h));
        }
        *(int4*)(P1 + base)        = *(const int4*)hi;
        *(int4*)(P1 + base + 2048) = *(const int4*)lo;
    }
}

// ---------------- 1-wave 64x64 MFMA GEMM, glds double-buffer, counted vmcnt ----------------
// EPI 0: C = f32 (+bias), EPI 1: C packed bf16 hi/lo tiles (+bias, relu), EPI 2: C bf16 row-major (+bias)

template<int EPI>
__global__ __launch_bounds__(64, 2) void mfma_gemm64_kernel(
    const short* __restrict__ Apk, const short* __restrict__ Wpk,
    const float* __restrict__ bias,
    float* __restrict__ Cf, short* __restrict__ Cpk,
    unsigned short* __restrict__ Cb, int M)
{
    __shared__ short As[2][4096];
    __shared__ short Bs[2][4096];

    const int bid = blockIdx.x;            // 0..1255 (=8*157)
    const int lin = (bid & 7) * RBLKS + (bid >> 3);
    const int rowblk = lin >> 3;
    const int colblk = lin & 7;

    const int lane = threadIdx.x;
    const int l15 = lane & 15;
    const int kg  = lane >> 4;
    const int kso = ((kg ^ ((l15 >> 1) & 3)) << 3);   // swizzled k-offset (lane-const)

    const short* Abase = Apk + (size_t)rowblk * 16 * 4096;
    const short* Bbase = Wpk + (size_t)colblk * 16 * 4096;

    f32x4 acc[4][4];
#pragma unroll
    for (int i = 0; i < 4; ++i)
#pragma unroll
        for (int j = 0; j < 4; ++j) acc[i][j] = (f32x4){0.f, 0.f, 0.f, 0.f};

    auto stage = [&](int buf, int kt) {
        const char* as = (const char*)(Abase + (size_t)kt * 4096);
        const char* bs = (const char*)(Bbase + (size_t)kt * 4096);
        char* ad = (char*)&As[buf][0];
        char* bd = (char*)&Bs[buf][0];
#pragma unroll
        for (int ii = 0; ii < 8; ++ii) {
            gld_lds16(as + ii * 1024 + lane * 16, ad + ii * 1024);
            gld_lds16(bs + ii * 1024 + lane * 16, bd + ii * 1024);
        }
    };

    stage(0, 0);

#pragma unroll
    for (int kt = 0; kt < 16; ++kt) {
        const int buf = kt & 1;
        if (kt < 15) {
            stage(buf ^ 1, kt + 1);
            asm volatile("s_waitcnt vmcnt(16)" ::: "memory");
        } else {
            asm volatile("s_waitcnt vmcnt(0)" ::: "memory");
        }
        __builtin_amdgcn_sched_barrier(0);

        bf16x8 af[4][2], bf[4][2];
#pragma unroll
        for (int m = 0; m < 4; ++m) {
            int ro = (m * 16 + l15) * 32 + kso;
            af[m][0] = *(const bf16x8*)&As[buf][ro];
            af[m][1] = *(const bf16x8*)&As[buf][2048 + ro];
        }
#pragma unroll
        for (int n = 0; n < 4; ++n) {
            int co = (n * 16 + l15) * 32 + kso;
            bf[n][0] = *(const bf16x8*)&Bs[buf][co];
            bf[n][1] = *(const bf16x8*)&Bs[buf][2048 + co];
        }
#pragma unroll
        for (int m = 0; m < 4; ++m)
#pragma unroll
            for (int n = 0; n < 4; ++n) {
                acc[m][n] = __builtin_amdgcn_mfma_f32_16x16x32_bf16(af[m][0], bf[n][0], acc[m][n], 0, 0, 0);
                acc[m][n] = __builtin_amdgcn_mfma_f32_16x16x32_bf16(af[m][0], bf[n][1], acc[m][n], 0, 0, 0);
                acc[m][n] = __builtin_amdgcn_mfma_f32_16x16x32_bf16(af[m][1], bf[n][0], acc[m][n], 0, 0, 0);
            }
    }

    if (EPI == 0) {
#pragma unroll
        for (int n = 0; n < 4; ++n) {
            int c = n * 16 + l15;
            float bv = bias[colblk * 64 + c];
#pragma unroll
            for (int m = 0; m < 4; ++m) {
                int r0 = rowblk * 64 + m * 16 + kg * 4;
#pragma unroll
                for (int j = 0; j < 4; ++j) {
                    int row = r0 + j;
                    if (row < M)
                        Cf[(size_t)row * 512 + colblk * 64 + c] = acc[m][n][j] + bv;
                }
            }
        }
    } else if (EPI == 2) {
        // bf16 row-major H for the aggregation gather
#pragma unroll
        for (int n = 0; n < 4; ++n) {
            int c = n * 16 + l15;
            float bv = bias[colblk * 64 + c];
#pragma unroll
            for (int m = 0; m < 4; ++m) {
                int r0 = rowblk * 64 + m * 16 + kg * 4;
#pragma unroll
                for (int j = 0; j < 4; ++j) {
                    int row = r0 + j;
                    if (row < M)
                        Cb[(size_t)row * 512 + colblk * 64 + c] = bf16_rne(acc[m][n][j] + bv);
                }
            }
        }
    } else {
#pragma unroll
        for (int n = 0; n < 4; ++n) {
            int c   = n * 16 + l15;          // 0..63
            int k_g = colblk * 64 + c;       // global k of next GEMM
            int kt_n = k_g >> 5, kk = k_g & 31, kgn = kk >> 3, kj = kk & 7;
            float bv = bias[k_g];
#pragma unroll
            for (int m = 0; m < 4; ++m) {
#pragma unroll
                for (int j = 0; j < 4; ++j) {
                    int rl  = m * 16 + kg * 4 + j;        // row within tile
                    int row = rowblk * 64 + rl;
                    float v = (row < M) ? fmaxf(acc[m][n][j] + bv, 0.f) : 0.f;
                    unsigned short h = bf16_rne(v);
                    unsigned short l = bf16_rne(v - bf16_to_f32(h));
                    size_t dst = (size_t)(rowblk * 16 + kt_n) * 4096 + rl * 32
                               + ((kgn ^ ((rl >> 1) & 3)) << 3) + kj;
                    Cpk[dst]        = (short)h;
                    Cpk[dst + 2048] = (short)l;
                }
            }
        }
    }
}

// ---------------- aggregation over bf16 H ----------------
// out[i,f] = sum_{e: dst=i} H[src_e,f]*norm_e + H[i,f]*dis[i]^2  (f32 accum/output)
// One block per node, 256 threads x ushort2 (feats 2t, 2t+1). 4-deep edge ILP.

__global__ __launch_bounds__(256) void aggregate_bf16_kernel(
    const unsigned short* __restrict__ Hb,
    const float* __restrict__ dis,
    const int* __restrict__ row_off,
    const int* __restrict__ csr_src,
    const float* __restrict__ csr_norm,
    float* __restrict__ out)
{
    const int node = blockIdx.x;
    const int t = threadIdx.x;
    const int start = row_off[node];
    const int end   = row_off[node + 1];
    const float dn = dis[node];
    const float sw = dn * dn;

    ushort2 hv = *((const ushort2*)(Hb + (size_t)node * DIM) + t);
    float a0 = bf16_to_f32(hv.x) * sw;
    float a1 = bf16_to_f32(hv.y) * sw;

    int e = start;
    for (; e + 3 < end; e += 4) {
        int s0 = csr_src[e],     s1 = csr_src[e + 1];
        int s2 = csr_src[e + 2], s3 = csr_src[e + 3];
        float w0 = csr_norm[e],     w1 = csr_norm[e + 1];
        float w2 = csr_norm[e + 2], w3 = csr_norm[e + 3];
        ushort2 v0 = *((const ushort2*)(Hb + (size_t)s0 * DIM) + t);
        ushort2 v1 = *((const ushort2*)(Hb + (size_t)s1 * DIM) + t);
        ushort2 v2 = *((const ushort2*)(Hb + (size_t)s2 * DIM) + t);
        ushort2 v3 = *((const ushort2*)(Hb + (size_t)s3 * DIM) + t);
        a0 += bf16_to_f32(v0.x) * w0 + bf16_to_f32(v1.x) * w1
            + bf16_to_f32(v2.x) * w2 + bf16_to_f32(v3.x) * w3;
        a1 += bf16_to_f32(v0.y) * w0 + bf16_to_f32(v1.y) * w1
            + bf16_to_f32(v2.y) * w2 + bf16_to_f32(v3.y) * w3;
    }
    for (; e < end; ++e) {
        int s = csr_src[e];
        float w = csr_norm[e];
        ushort2 v = *((const ushort2*)(Hb + (size_t)s * DIM) + t);
        a0 += bf16_to_f32(v.x) * w;
        a1 += bf16_to_f32(v.y) * w;
    }
    float2 r = make_float2(a0, a1);
    *((float2*)(out + (size_t)node * DIM) + t) = r;
}

// ---------------- launch ----------------

extern "C" void kernel_launch(void* const* d_in, const int* in_sizes, int n_in,
                              void* d_out, int out_size, void* d_ws, size_t ws_size,
                              hipStream_t stream) {
    const float* x   = (const float*)d_in[0];
    const int*   ei  = (const int*)d_in[1];
    const float* W1  = (const float*)d_in[2];
    const float* b1  = (const float*)d_in[3];
    const float* W2  = (const float*)d_in[4];
    const float* b2  = (const float*)d_in[5];
    const float* Wp1 = (const float*)d_in[6];
    const float* bp1 = (const float*)d_in[7];
    const float* Wp2 = (const float*)d_in[8];
    const float* bp2 = (const float*)d_in[9];

    float* out  = (float*)d_out;
    float* z    = out + (size_t)N_NODES * DIM;
    float* proj = z   + (size_t)N_NODES * DIM;

    char* ws = (char*)d_ws;
    size_t off = 0;
    auto walloc = [&](size_t bytes) -> void* {
        void* p = ws + off;
        off = (off + bytes + 255) & ~(size_t)255;
        return p;
    };
    const size_t PK_SHORTS = (size_t)RBLKS * 16 * 4096;
    unsigned short* Hb = (unsigned short*)walloc((size_t)N_NODES * DIM * sizeof(unsigned short)); // 10.24 MB
    short* APK0 = (short*)walloc(PK_SHORTS * sizeof(short));
    short* ZPKp = (short*)walloc(PK_SHORTS * sizeof(short));
    short* ZPKr = (short*)walloc(PK_SHORTS * sizeof(short));
    short* WT1  = (short*)walloc((size_t)8 * 16 * 4096 * sizeof(short));
    short* WT2  = (short*)walloc((size_t)8 * 16 * 4096 * sizeof(short));
    short* WTp1 = (short*)walloc((size_t)8 * 16 * 4096 * sizeof(short));
    short* WTp2 = (short*)walloc((size_t)8 * 16 * 4096 * sizeof(short));
    int*   deg      = (int*)  walloc(N_NODES * sizeof(int));
    int*   cursor   = (int*)  walloc(N_NODES * sizeof(int));
    int*   row_off  = (int*)  walloc((N_NODES + 1) * sizeof(int));
    float* dis      = (float*)walloc(N_NODES * sizeof(float));
    int*   csr_src  = (int*)  walloc(N_EDGES * sizeof(int));
    float* csr_norm = (float*)walloc(N_EDGES * sizeof(float));

    const dim3 blk(256);
    const dim3 gN((N_NODES + 255) / 256);
    const dim3 gE((N_EDGES + 255) / 256);
    const dim3 pk_grid(16, RBLKS);
    const dim3 gemm_grid(8 * RBLKS);
    const dim3 wave(64);

    pack_weight_kernel<<<128, blk, 0, stream>>>(W1,  WT1);
    pack_weight_kernel<<<128, blk, 0, stream>>>(W2,  WT2);
    pack_weight_kernel<<<128, blk, 0, stream>>>(Wp1, WTp1);
    pack_weight_kernel<<<128, blk, 0, stream>>>(Wp2, WTp2);
    pack_a_kernel<false><<<pk_grid, blk, 0, stream>>>(x, APK0, nullptr, N_NODES);

    zero_int_kernel<<<gN, blk, 0, stream>>>(deg, N_NODES);
    zero_int_kernel<<<gN, blk, 0, stream>>>(cursor, N_NODES);
    count_deg_kernel<<<gE, blk, 0, stream>>>(ei, deg, N_EDGES);
    dis_kernel<<<gN, blk, 0, stream>>>(deg, dis, N_NODES);
    scan_kernel<<<1, 1024, 0, stream>>>(deg, row_off, N_NODES);
    scatter_kernel<<<gE, blk, 0, stream>>>(ei, dis, row_off, cursor, csr_src, csr_norm, N_EDGES);

    // z = aggregate(x @ W1 + b1)
    mfma_gemm64_kernel<2><<<gemm_grid, wave, 0, stream>>>(APK0, WT1, b1, nullptr, nullptr, Hb, N_NODES);
    aggregate_bf16_kernel<<<N_NODES, blk, 0, stream>>>(Hb, dis, row_off, csr_src, csr_norm, z);

    // pack z (plain + relu)
    pack_a_kernel<true><<<pk_grid, blk, 0, stream>>>(z, ZPKp, ZPKr, N_NODES);

    // out = aggregate(relu(z) @ W2 + b2)
    mfma_gemm64_kernel<2><<<gemm_grid, wave, 0, stream>>>(ZPKr, WT2, b2, nullptr, nullptr, Hb, N_NODES);
    aggregate_bf16_kernel<<<N_NODES, blk, 0, stream>>>(Hb, dis, row_off, csr_src, csr_norm, out);

    // P1 = relu(z @ Wp1 + bp1), written packed; proj = P1 @ Wp2 + bp2
    mfma_gemm64_kernel<1><<<gemm_grid, wave, 0, stream>>>(ZPKp, WTp1, bp1, nullptr, APK0, nullptr, N_NODES);
    mfma_gemm64_kernel<0><<<gemm_grid, wave, 0, stream>>>(APK0, WTp2, bp2, proj, nullptr, nullptr, N_NODES);
}

// Round 6
// 269.775 us; speedup vs baseline: 1.3776x; 1.0516x over previous
//
#include <hip/hip_runtime.h>
#include <stddef.h>

#define N_NODES 10000
#define N_EDGES 160000
#define DIM     512
#define RBLKS   157   // ceil(10000/64)

typedef short bf16x8 __attribute__((ext_vector_type(8)));
typedef float f32x4  __attribute__((ext_vector_type(4)));

__device__ inline unsigned short bf16_rne(float f) {
    unsigned u = __builtin_bit_cast(unsigned, f);
    u += 0x7FFF + ((u >> 16) & 1);
    return (unsigned short)(u >> 16);
}
__device__ inline float bf16_to_f32(unsigned short h) {
    unsigned u = ((unsigned)h) << 16;
    return __builtin_bit_cast(float, u);
}

__device__ inline void gld_lds16(const void* g, void* lds) {
    __builtin_amdgcn_global_load_lds(
        (const __attribute__((address_space(1))) void*)g,
        (__attribute__((address_space(3))) void*)lds, 16, 0, 0);
}

// ---------------- graph preprocessing (unchanged, verified) ----------------

__global__ void zero_int_kernel(int* __restrict__ p, int n) {
    int i = blockIdx.x * blockDim.x + threadIdx.x;
    if (i < n) p[i] = 0;
}

__global__ void count_deg_kernel(const int* __restrict__ ei, int* __restrict__ deg, int E) {
    int e = blockIdx.x * blockDim.x + threadIdx.x;
    if (e < E) atomicAdd(&deg[ei[E + e]], 1);
}

__global__ void dis_kernel(const int* __restrict__ deg, float* __restrict__ dis, int n) {
    int i = blockIdx.x * blockDim.x + threadIdx.x;
    if (i < n) dis[i] = rsqrtf((float)(deg[i] + 1));
}

__global__ void scan_kernel(const int* __restrict__ deg, int* __restrict__ row_off, int n) {
    __shared__ int sm[1024];
    __shared__ int carry_s;
    if (threadIdx.x == 0) carry_s = 0;
    __syncthreads();
    for (int base = 0; base < n; base += 1024) {
        int i = base + (int)threadIdx.x;
        int v = (i < n) ? deg[i] : 0;
        sm[threadIdx.x] = v;
        __syncthreads();
        for (int off = 1; off < 1024; off <<= 1) {
            int t = (threadIdx.x >= (unsigned)off) ? sm[threadIdx.x - off] : 0;
            __syncthreads();
            sm[threadIdx.x] += t;
            __syncthreads();
        }
        int carry = carry_s;
        if (i < n) row_off[i + 1] = sm[threadIdx.x] + carry;
        __syncthreads();
        if (threadIdx.x == 1023) carry_s = carry + sm[1023];
        __syncthreads();
    }
    if (threadIdx.x == 0) row_off[0] = 0;
}

__global__ void scatter_kernel(const int* __restrict__ ei, const float* __restrict__ dis,
                               const int* __restrict__ row_off, int* __restrict__ cursor,
                               int* __restrict__ csr_src, float* __restrict__ csr_norm, int E) {
    int e = blockIdx.x * blockDim.x + threadIdx.x;
    if (e >= E) return;
    int s = ei[e];
    int d = ei[E + e];
    int slot = row_off[d] + atomicAdd(&cursor[d], 1);
    csr_src[slot]  = s;
    csr_norm[slot] = dis[s] * dis[d];
}

// ---------------- packing ----------------
// Tile layout (shorts): [blk][kt 16][arr 2(hi/lo)][idx 64][k 32], tile = 4096 shorts.
// XOR swizzle baked in: k-group slot kq stored at (kq ^ ((idx>>1)&3)).

__global__ __launch_bounds__(256) void pack_weight_kernel(const float* __restrict__ W,
                                                          short* __restrict__ WT) {
    int id = blockIdx.x * 256 + threadIdx.x;   // 32768
    int n  = id & 511;                         // coalesced over n
    int kc = id >> 9;                          // k-chunk of 8, 0..63
    int colblk = n >> 6, col = n & 63;
    int kt = kc >> 2, kq = kc & 3;
    short hi[8], lo[8];
#pragma unroll
    for (int j = 0; j < 8; ++j) {
        float v = W[(size_t)(kc * 8 + j) * 512 + n];
        unsigned short h = bf16_rne(v);
        hi[j] = (short)h;
        lo[j] = (short)bf16_rne(v - bf16_to_f32(h));
    }
    size_t base = (size_t)(colblk * 16 + kt) * 4096 + col * 32 + ((kq ^ ((col >> 1) & 3)) << 3);
    *(int4*)(WT + base)        = *(const int4*)hi;
    *(int4*)(WT + base + 2048) = *(const int4*)lo;
}

// pack A[M,512] f32 -> P0 (plain), and if DUAL also P1 (relu'd)
template<bool DUAL>
__global__ __launch_bounds__(256) void pack_a_kernel(const float* __restrict__ A,
                                                     short* __restrict__ P0,
                                                     short* __restrict__ P1, int M) {
    const int kt = blockIdx.x;         // 0..15
    const int rb = blockIdx.y;         // 0..RBLKS-1
    const int t  = threadIdx.x;
    const int r  = t >> 2;             // 0..63
    const int kq = t & 3;
    const int row = rb * 64 + r;
    float v[8] = {};
    if (row < M) {
        float4 a = *(const float4*)(A + (size_t)row * 512 + kt * 32 + kq * 8);
        float4 b = *(const float4*)(A + (size_t)row * 512 + kt * 32 + kq * 8 + 4);
        v[0]=a.x; v[1]=a.y; v[2]=a.z; v[3]=a.w; v[4]=b.x; v[5]=b.y; v[6]=b.z; v[7]=b.w;
    }
    size_t base = (size_t)(rb * 16 + kt) * 4096 + r * 32 + ((kq ^ ((r >> 1) & 3)) << 3);
    short hi[8], lo[8];
#pragma unroll
    for (int j = 0; j < 8; ++j) {
        unsigned short h = bf16_rne(v[j]);
        hi[j] = (short)h;
        lo[j] = (short)bf16_rne(v[j] - bf16_to_f32(h));
    }
    *(int4*)(P0 + base)        = *(const int4*)hi;
    *(int4*)(P0 + base + 2048) = *(const int4*)lo;
    if (DUAL) {
#pragma unroll
        for (int j = 0; j < 8; ++j) {
            float rv = fmaxf(v[j], 0.f);
            unsigned short h = bf16_rne(rv);
            hi[j] = (short)h;
            lo[j] = (short)bf16_rne(rv - bf16_to_f32(h));
        }
        *(int4*)(P1 + base)        = *(const int4*)hi;
        *(int4*)(P1 + base + 2048) = *(const int4*)lo;
    }
}

// ---------------- 1-wave 64x64 MFMA GEMM, 3-deep glds pipeline, counted vmcnt ----------------
// EPI 0: C = f32 (+bias), EPI 1: C packed bf16 hi/lo tiles (+bias, relu), EPI 2: C bf16 row-major (+bias)

template<int EPI>
__global__ __launch_bounds__(64) void mfma_gemm64_kernel(
    const short* __restrict__ Apk, const short* __restrict__ Wpk,
    const float* __restrict__ bias,
    float* __restrict__ Cf, short* __restrict__ Cpk,
    unsigned short* __restrict__ Cb, int M)
{
    __shared__ short As[3][4096];   // 3-deep pipeline, 24 KB
    __shared__ short Bs[3][4096];   // 24 KB

    const int bid = blockIdx.x;            // 0..1255 (=8*157)
    const int lin = (bid & 7) * RBLKS + (bid >> 3);
    const int rowblk = lin >> 3;
    const int colblk = lin & 7;

    const int lane = threadIdx.x;
    const int l15 = lane & 15;
    const int kg  = lane >> 4;
    const int kso = ((kg ^ ((l15 >> 1) & 3)) << 3);   // swizzled k-offset (lane-const)

    const short* Abase = Apk + (size_t)rowblk * 16 * 4096;
    const short* Bbase = Wpk + (size_t)colblk * 16 * 4096;

    f32x4 acc[4][4];
#pragma unroll
    for (int i = 0; i < 4; ++i)
#pragma unroll
        for (int j = 0; j < 4; ++j) acc[i][j] = (f32x4){0.f, 0.f, 0.f, 0.f};

    auto stage = [&](int buf, int kt) {
        const char* as = (const char*)(Abase + (size_t)kt * 4096);
        const char* bs = (const char*)(Bbase + (size_t)kt * 4096);
        char* ad = (char*)&As[buf][0];
        char* bd = (char*)&Bs[buf][0];
#pragma unroll
        for (int ii = 0; ii < 8; ++ii) {
            gld_lds16(as + ii * 1024 + lane * 16, ad + ii * 1024);
            gld_lds16(bs + ii * 1024 + lane * 16, bd + ii * 1024);
        }
    };

    // prologue: prefetch tiles 0 and 1
    stage(0, 0);
    stage(1, 1);

#pragma unroll
    for (int kt = 0; kt < 16; ++kt) {
        const int buf = kt % 3;
        // stage 2-ahead into the buffer freed last iteration, then wait for
        // the CURRENT tile only (2 younger tiles = 32 loads stay in flight).
        if (kt <= 13) {
            stage((kt + 2) % 3, kt + 2);
            asm volatile("s_waitcnt vmcnt(32)" ::: "memory");
        } else if (kt == 14) {
            asm volatile("s_waitcnt vmcnt(16)" ::: "memory");
        } else {
            asm volatile("s_waitcnt vmcnt(0)" ::: "memory");
        }
        __builtin_amdgcn_sched_barrier(0);

        bf16x8 af[4][2], bf[4][2];
#pragma unroll
        for (int m = 0; m < 4; ++m) {
            int ro = (m * 16 + l15) * 32 + kso;
            af[m][0] = *(const bf16x8*)&As[buf][ro];
            af[m][1] = *(const bf16x8*)&As[buf][2048 + ro];
        }
#pragma unroll
        for (int n = 0; n < 4; ++n) {
            int co = (n * 16 + l15) * 32 + kso;
            bf[n][0] = *(const bf16x8*)&Bs[buf][co];
            bf[n][1] = *(const bf16x8*)&Bs[buf][2048 + co];
        }
#pragma unroll
        for (int m = 0; m < 4; ++m)
#pragma unroll
            for (int n = 0; n < 4; ++n) {
                acc[m][n] = __builtin_amdgcn_mfma_f32_16x16x32_bf16(af[m][0], bf[n][0], acc[m][n], 0, 0, 0);
                acc[m][n] = __builtin_amdgcn_mfma_f32_16x16x32_bf16(af[m][0], bf[n][1], acc[m][n], 0, 0, 0);
                acc[m][n] = __builtin_amdgcn_mfma_f32_16x16x32_bf16(af[m][1], bf[n][0], acc[m][n], 0, 0, 0);
            }
    }

    if (EPI == 0) {
#pragma unroll
        for (int n = 0; n < 4; ++n) {
            int c = n * 16 + l15;
            float bv = bias[colblk * 64 + c];
#pragma unroll
            for (int m = 0; m < 4; ++m) {
                int r0 = rowblk * 64 + m * 16 + kg * 4;
#pragma unroll
                for (int j = 0; j < 4; ++j) {
                    int row = r0 + j;
                    if (row < M)
                        Cf[(size_t)row * 512 + colblk * 64 + c] = acc[m][n][j] + bv;
                }
            }
        }
    } else if (EPI == 2) {
        // bf16 row-major H for the aggregation gather
#pragma unroll
        for (int n = 0; n < 4; ++n) {
            int c = n * 16 + l15;
            float bv = bias[colblk * 64 + c];
#pragma unroll
            for (int m = 0; m < 4; ++m) {
                int r0 = rowblk * 64 + m * 16 + kg * 4;
#pragma unroll
                for (int j = 0; j < 4; ++j) {
                    int row = r0 + j;
                    if (row < M)
                        Cb[(size_t)row * 512 + colblk * 64 + c] = bf16_rne(acc[m][n][j] + bv);
                }
            }
        }
    } else {
#pragma unroll
        for (int n = 0; n < 4; ++n) {
            int c   = n * 16 + l15;          // 0..63
            int k_g = colblk * 64 + c;       // global k of next GEMM
            int kt_n = k_g >> 5, kk = k_g & 31, kgn = kk >> 3, kj = kk & 7;
            float bv = bias[k_g];
#pragma unroll
            for (int m = 0; m < 4; ++m) {
#pragma unroll
                for (int j = 0; j < 4; ++j) {
                    int rl  = m * 16 + kg * 4 + j;        // row within tile
                    int row = rowblk * 64 + rl;
                    float v = (row < M) ? fmaxf(acc[m][n][j] + bv, 0.f) : 0.f;
                    unsigned short h = bf16_rne(v);
                    unsigned short l = bf16_rne(v - bf16_to_f32(h));
                    size_t dst = (size_t)(rowblk * 16 + kt_n) * 4096 + rl * 32
                               + ((kgn ^ ((rl >> 1) & 3)) << 3) + kj;
                    Cpk[dst]        = (short)h;
                    Cpk[dst + 2048] = (short)l;
                }
            }
        }
    }
}

// ---------------- aggregation over bf16 H ----------------
// out[i,f] = sum_{e: dst=i} H[src_e,f]*norm_e + H[i,f]*dis[i]^2  (f32 accum/output)
// One block per node, 256 threads x ushort2 (feats 2t, 2t+1). 4-deep edge ILP.

__global__ __launch_bounds__(256) void aggregate_bf16_kernel(
    const unsigned short* __restrict__ Hb,
    const float* __restrict__ dis,
    const int* __restrict__ row_off,
    const int* __restrict__ csr_src,
    const float* __restrict__ csr_norm,
    float* __restrict__ out)
{
    const int node = blockIdx.x;
    const int t = threadIdx.x;
    const int start = row_off[node];
    const int end   = row_off[node + 1];
    const float dn = dis[node];
    const float sw = dn * dn;

    ushort2 hv = *((const ushort2*)(Hb + (size_t)node * DIM) + t);
    float a0 = bf16_to_f32(hv.x) * sw;
    float a1 = bf16_to_f32(hv.y) * sw;

    int e = start;
    for (; e + 3 < end; e += 4) {
        int s0 = csr_src[e],     s1 = csr_src[e + 1];
        int s2 = csr_src[e + 2], s3 = csr_src[e + 3];
        float w0 = csr_norm[e],     w1 = csr_norm[e + 1];
        float w2 = csr_norm[e + 2], w3 = csr_norm[e + 3];
        ushort2 v0 = *((const ushort2*)(Hb + (size_t)s0 * DIM) + t);
        ushort2 v1 = *((const ushort2*)(Hb + (size_t)s1 * DIM) + t);
        ushort2 v2 = *((const ushort2*)(Hb + (size_t)s2 * DIM) + t);
        ushort2 v3 = *((const ushort2*)(Hb + (size_t)s3 * DIM) + t);
        a0 += bf16_to_f32(v0.x) * w0 + bf16_to_f32(v1.x) * w1
            + bf16_to_f32(v2.x) * w2 + bf16_to_f32(v3.x) * w3;
        a1 += bf16_to_f32(v0.y) * w0 + bf16_to_f32(v1.y) * w1
            + bf16_to_f32(v2.y) * w2 + bf16_to_f32(v3.y) * w3;
    }
    for (; e < end; ++e) {
        int s = csr_src[e];
        float w = csr_norm[e];
        ushort2 v = *((const ushort2*)(Hb + (size_t)s * DIM) + t);
        a0 += bf16_to_f32(v.x) * w;
        a1 += bf16_to_f32(v.y) * w;
    }
    float2 r = make_float2(a0, a1);
    *((float2*)(out + (size_t)node * DIM) + t) = r;
}

// ---------------- launch ----------------

extern "C" void kernel_launch(void* const* d_in, const int* in_sizes, int n_in,
                              void* d_out, int out_size, void* d_ws, size_t ws_size,
                              hipStream_t stream) {
    const float* x   = (const float*)d_in[0];
    const int*   ei  = (const int*)d_in[1];
    const float* W1  = (const float*)d_in[2];
    const float* b1  = (const float*)d_in[3];
    const float* W2  = (const float*)d_in[4];
    const float* b2  = (const float*)d_in[5];
    const float* Wp1 = (const float*)d_in[6];
    const float* bp1 = (const float*)d_in[7];
    const float* Wp2 = (const float*)d_in[8];
    const float* bp2 = (const float*)d_in[9];

    float* out  = (float*)d_out;
    float* z    = out + (size_t)N_NODES * DIM;
    float* proj = z   + (size_t)N_NODES * DIM;

    char* ws = (char*)d_ws;
    size_t off = 0;
    auto walloc = [&](size_t bytes) -> void* {
        void* p = ws + off;
        off = (off + bytes + 255) & ~(size_t)255;
        return p;
    };
    const size_t PK_SHORTS = (size_t)RBLKS * 16 * 4096;
    unsigned short* Hb = (unsigned short*)walloc((size_t)N_NODES * DIM * sizeof(unsigned short)); // 10.24 MB
    short* APK0 = (short*)walloc(PK_SHORTS * sizeof(short));
    short* ZPKp = (short*)walloc(PK_SHORTS * sizeof(short));
    short* ZPKr = (short*)walloc(PK_SHORTS * sizeof(short));
    short* WT1  = (short*)walloc((size_t)8 * 16 * 4096 * sizeof(short));
    short* WT2  = (short*)walloc((size_t)8 * 16 * 4096 * sizeof(short));
    short* WTp1 = (short*)walloc((size_t)8 * 16 * 4096 * sizeof(short));
    short* WTp2 = (short*)walloc((size_t)8 * 16 * 4096 * sizeof(short));
    int*   deg      = (int*)  walloc(N_NODES * sizeof(int));
    int*   cursor   = (int*)  walloc(N_NODES * sizeof(int));
    int*   row_off  = (int*)  walloc((N_NODES + 1) * sizeof(int));
    float* dis      = (float*)walloc(N_NODES * sizeof(float));
    int*   csr_src  = (int*)  walloc(N_EDGES * sizeof(int));
    float* csr_norm = (float*)walloc(N_EDGES * sizeof(float));

    const dim3 blk(256);
    const dim3 gN((N_NODES + 255) / 256);
    const dim3 gE((N_EDGES + 255) / 256);
    const dim3 pk_grid(16, RBLKS);
    const dim3 gemm_grid(8 * RBLKS);
    const dim3 wave(64);

    pack_weight_kernel<<<128, blk, 0, stream>>>(W1,  WT1);
    pack_weight_kernel<<<128, blk, 0, stream>>>(W2,  WT2);
    pack_weight_kernel<<<128, blk, 0, stream>>>(Wp1, WTp1);
    pack_weight_kernel<<<128, blk, 0, stream>>>(Wp2, WTp2);
    pack_a_kernel<false><<<pk_grid, blk, 0, stream>>>(x, APK0, nullptr, N_NODES);

    zero_int_kernel<<<gN, blk, 0, stream>>>(deg, N_NODES);
    zero_int_kernel<<<gN, blk, 0, stream>>>(cursor, N_NODES);
    count_deg_kernel<<<gE, blk, 0, stream>>>(ei, deg, N_EDGES);
    dis_kernel<<<gN, blk, 0, stream>>>(deg, dis, N_NODES);
    scan_kernel<<<1, 1024, 0, stream>>>(deg, row_off, N_NODES);
    scatter_kernel<<<gE, blk, 0, stream>>>(ei, dis, row_off, cursor, csr_src, csr_norm, N_EDGES);

    // z = aggregate(x @ W1 + b1)
    mfma_gemm64_kernel<2><<<gemm_grid, wave, 0, stream>>>(APK0, WT1, b1, nullptr, nullptr, Hb, N_NODES);
    aggregate_bf16_kernel<<<N_NODES, blk, 0, stream>>>(Hb, dis, row_off, csr_src, csr_norm, z);

    // pack z (plain + relu)
    pack_a_kernel<true><<<pk_grid, blk, 0, stream>>>(z, ZPKp, ZPKr, N_NODES);

    // out = aggregate(relu(z) @ W2 + b2)
    mfma_gemm64_kernel<2><<<gemm_grid, wave, 0, stream>>>(ZPKr, WT2, b2, nullptr, nullptr, Hb, N_NODES);
    aggregate_bf16_kernel<<<N_NODES, blk, 0, stream>>>(Hb, dis, row_off, csr_src, csr_norm, out);

    // P1 = relu(z @ Wp1 + bp1), written packed; proj = P1 @ Wp2 + bp2
    mfma_gemm64_kernel<1><<<gemm_grid, wave, 0, stream>>>(ZPKp, WTp1, bp1, nullptr, APK0, nullptr, N_NODES);
    mfma_gemm64_kernel<0><<<gemm_grid, wave, 0, stream>>>(APK0, WTp2, bp2, proj, nullptr, nullptr, N_NODES);
}

// Round 7
// 267.146 us; speedup vs baseline: 1.3912x; 1.0098x over previous
//
#include <hip/hip_runtime.h>
#include <stddef.h>

#define N_NODES 10000
#define N_EDGES 160000
#define DIM     512
#define RBLKS   157   // ceil(10000/64)
#define SCAN_BLKS 40  // ceil(10000/256)

typedef short bf16x8 __attribute__((ext_vector_type(8)));
typedef float f32x4  __attribute__((ext_vector_type(4)));

__device__ inline unsigned short bf16_rne(float f) {
    unsigned u = __builtin_bit_cast(unsigned, f);
    u += 0x7FFF + ((u >> 16) & 1);
    return (unsigned short)(u >> 16);
}
__device__ inline float bf16_to_f32(unsigned short h) {
    unsigned u = ((unsigned)h) << 16;
    return __builtin_bit_cast(float, u);
}

// ---------------- graph preprocessing ----------------

__global__ void zero_int_kernel(int* __restrict__ p, int n) {
    int i = blockIdx.x * blockDim.x + threadIdx.x;
    if (i < n) p[i] = 0;
}

__global__ void count_deg_kernel(const int* __restrict__ ei, int* __restrict__ deg, int E) {
    int e = blockIdx.x * blockDim.x + threadIdx.x;
    if (e < E) atomicAdd(&deg[ei[E + e]], 1);
}

// block-local inclusive scan of deg; also computes dis and zeroes cursor
__global__ __launch_bounds__(256) void scan1_kernel(const int* __restrict__ deg,
                                                    int* __restrict__ row_off,
                                                    int* __restrict__ bsum,
                                                    float* __restrict__ dis,
                                                    int* __restrict__ cursor, int n) {
    __shared__ int sm[256];
    const int i = blockIdx.x * 256 + threadIdx.x;
    int v = (i < n) ? deg[i] : 0;
    if (i < n) {
        dis[i] = rsqrtf((float)(v + 1));   // +1 self-loop
        cursor[i] = 0;
    }
    sm[threadIdx.x] = v;
    __syncthreads();
    for (int off = 1; off < 256; off <<= 1) {
        int t = (threadIdx.x >= (unsigned)off) ? sm[threadIdx.x - off] : 0;
        __syncthreads();
        sm[threadIdx.x] += t;
        __syncthreads();
    }
    if (i < n) row_off[i + 1] = sm[threadIdx.x];          // local inclusive
    if (threadIdx.x == 255) bsum[blockIdx.x] = sm[255];
}

// wave-scan of the SCAN_BLKS block sums -> exclusive
__global__ __launch_bounds__(64) void scan2_kernel(int* __restrict__ bsum) {
    const int lane = threadIdx.x;
    int v0 = (lane < SCAN_BLKS) ? bsum[lane] : 0;
    int v = v0;
    for (int off = 1; off < 64; off <<= 1) {
        int t = __shfl_up(v, off, 64);
        if (lane >= off) v += t;
    }
    if (lane < SCAN_BLKS) bsum[lane] = v - v0;            // exclusive
}

__global__ __launch_bounds__(256) void scan3_kernel(int* __restrict__ row_off,
                                                    const int* __restrict__ bsum, int n) {
    const int i = blockIdx.x * 256 + threadIdx.x;
    if (i < n) row_off[i + 1] += bsum[blockIdx.x];
    if (i == 0) row_off[0] = 0;
}

__global__ void scatter_kernel(const int* __restrict__ ei, const float* __restrict__ dis,
                               const int* __restrict__ row_off, int* __restrict__ cursor,
                               int* __restrict__ csr_src, float* __restrict__ csr_norm, int E) {
    int e = blockIdx.x * blockDim.x + threadIdx.x;
    if (e >= E) return;
    int s = ei[e];
    int d = ei[E + e];
    int slot = row_off[d] + atomicAdd(&cursor[d], 1);
    csr_src[slot]  = s;
    csr_norm[slot] = dis[s] * dis[d];
}

// ---------------- packing ----------------
// Tile layout (shorts): [blk][kt 16][arr 2(hi/lo)][idx 64][k 32], tile = 4096 shorts.
// XOR permutation baked in: k-group kq stored at (kq ^ ((idx>>1)&3)) — a pure
// within-1KB permutation; GEMM reads with the same mapping.

__global__ __launch_bounds__(256) void pack_weights4_kernel(
    const float* __restrict__ W1, const float* __restrict__ W2,
    const float* __restrict__ Wp1, const float* __restrict__ Wp2,
    short* __restrict__ T1, short* __restrict__ T2,
    short* __restrict__ Tp1, short* __restrict__ Tp2) {
    const int wsel = blockIdx.x >> 7;
    const float* W = (wsel == 0) ? W1 : (wsel == 1) ? W2 : (wsel == 2) ? Wp1 : Wp2;
    short* WT      = (wsel == 0) ? T1 : (wsel == 1) ? T2 : (wsel == 2) ? Tp1 : Tp2;
    int id = (blockIdx.x & 127) * 256 + threadIdx.x;   // 32768 per weight
    int n  = id & 511;
    int kc = id >> 9;
    int colblk = n >> 6, col = n & 63;
    int kt = kc >> 2, kq = kc & 3;
    short hi[8], lo[8];
#pragma unroll
    for (int j = 0; j < 8; ++j) {
        float v = W[(size_t)(kc * 8 + j) * 512 + n];
        unsigned short h = bf16_rne(v);
        hi[j] = (short)h;
        lo[j] = (short)bf16_rne(v - bf16_to_f32(h));
    }
    size_t base = (size_t)(colblk * 16 + kt) * 4096 + col * 32 + ((kq ^ ((col >> 1) & 3)) << 3);
    *(int4*)(WT + base)        = *(const int4*)hi;
    *(int4*)(WT + base + 2048) = *(const int4*)lo;
}

template<bool DUAL>
__global__ __launch_bounds__(256) void pack_a_kernel(const float* __restrict__ A,
                                                     short* __restrict__ P0,
                                                     short* __restrict__ P1, int M) {
    const int kt = blockIdx.x;
    const int rb = blockIdx.y;
    const int t  = threadIdx.x;
    const int r  = t >> 2;
    const int kq = t & 3;
    const int row = rb * 64 + r;
    float v[8] = {};
    if (row < M) {
        float4 a = *(const float4*)(A + (size_t)row * 512 + kt * 32 + kq * 8);
        float4 b = *(const float4*)(A + (size_t)row * 512 + kt * 32 + kq * 8 + 4);
        v[0]=a.x; v[1]=a.y; v[2]=a.z; v[3]=a.w; v[4]=b.x; v[5]=b.y; v[6]=b.z; v[7]=b.w;
    }
    size_t base = (size_t)(rb * 16 + kt) * 4096 + r * 32 + ((kq ^ ((r >> 1) & 3)) << 3);
    short hi[8], lo[8];
#pragma unroll
    for (int j = 0; j < 8; ++j) {
        unsigned short h = bf16_rne(v[j]);
        hi[j] = (short)h;
        lo[j] = (short)bf16_rne(v[j] - bf16_to_f32(h));
    }
    *(int4*)(P0 + base)        = *(const int4*)hi;
    *(int4*)(P0 + base + 2048) = *(const int4*)lo;
    if (DUAL) {
#pragma unroll
        for (int j = 0; j < 8; ++j) {
            float rv = fmaxf(v[j], 0.f);
            unsigned short h = bf16_rne(rv);
            hi[j] = (short)h;
            lo[j] = (short)bf16_rne(rv - bf16_to_f32(h));
        }
        *(int4*)(P1 + base)        = *(const int4*)hi;
        *(int4*)(P1 + base + 2048) = *(const int4*)lo;
    }
}

// ---------------- 1-wave 64x64 MFMA GEMM, register-direct (no LDS) ----------------
// Operands are pre-packed in per-lane fragment order: each fragment load is one
// fully-coalesced 1KB segment (64 lanes x 16B). Register double-buffer, no barriers.
// EPI 0: C = f32 (+bias), EPI 1: C packed bf16 hi/lo tiles (+bias, relu), EPI 2: C bf16 row-major (+bias)

template<int EPI>
__global__ __launch_bounds__(64) void mfma_gemm64_kernel(
    const short* __restrict__ Apk, const short* __restrict__ Wpk,
    const float* __restrict__ bias,
    float* __restrict__ Cf, short* __restrict__ Cpk,
    unsigned short* __restrict__ Cb, int M)
{
    const int bid = blockIdx.x;            // 0..1255 (=8*157)
    const int lin = (bid & 7) * RBLKS + (bid >> 3);   // XCD-chunked swizzle
    const int rowblk = lin >> 3;
    const int colblk = lin & 7;

    const int lane = threadIdx.x;
    const int l15 = lane & 15;
    const int kg  = lane >> 4;
    const int kso = ((kg ^ ((l15 >> 1) & 3)) << 3);   // baked permutation (lane-const)

    const short* Ab = Apk + (size_t)rowblk * 16 * 4096;
    const short* Bb = Wpk + (size_t)colblk * 16 * 4096;

    f32x4 acc[4][4];
#pragma unroll
    for (int i = 0; i < 4; ++i)
#pragma unroll
        for (int j = 0; j < 4; ++j) acc[i][j] = (f32x4){0.f, 0.f, 0.f, 0.f};

    bf16x8 a[2][4][2], b[2][4][2];

    auto load = [&](int pb, int kt) {
        const short* ak = Ab + kt * 4096;
        const short* bk = Bb + kt * 4096;
#pragma unroll
        for (int m = 0; m < 4; ++m) {
            const int ro = (m * 16 + l15) * 32 + kso;
#pragma unroll
            for (int s = 0; s < 2; ++s) {
                a[pb][m][s] = *(const bf16x8*)(ak + s * 2048 + ro);
                b[pb][m][s] = *(const bf16x8*)(bk + s * 2048 + ro);
            }
        }
    };

    load(0, 0);

#pragma unroll
    for (int kt = 0; kt < 16; ++kt) {
        const int cur = kt & 1;
        if (kt < 15) load(cur ^ 1, kt + 1);   // prefetch next tile into regs
#pragma unroll
        for (int m = 0; m < 4; ++m)
#pragma unroll
            for (int n = 0; n < 4; ++n) {
                acc[m][n] = __builtin_amdgcn_mfma_f32_16x16x32_bf16(a[cur][m][0], b[cur][n][0], acc[m][n], 0, 0, 0);
                acc[m][n] = __builtin_amdgcn_mfma_f32_16x16x32_bf16(a[cur][m][0], b[cur][n][1], acc[m][n], 0, 0, 0);
                acc[m][n] = __builtin_amdgcn_mfma_f32_16x16x32_bf16(a[cur][m][1], b[cur][n][0], acc[m][n], 0, 0, 0);
            }
    }

    if (EPI == 0) {
#pragma unroll
        for (int n = 0; n < 4; ++n) {
            int c = n * 16 + l15;
            float bv = bias[colblk * 64 + c];
#pragma unroll
            for (int m = 0; m < 4; ++m) {
                int r0 = rowblk * 64 + m * 16 + kg * 4;
#pragma unroll
                for (int j = 0; j < 4; ++j) {
                    int row = r0 + j;
                    if (row < M)
                        Cf[(size_t)row * 512 + colblk * 64 + c] = acc[m][n][j] + bv;
                }
            }
        }
    } else if (EPI == 2) {
#pragma unroll
        for (int n = 0; n < 4; ++n) {
            int c = n * 16 + l15;
            float bv = bias[colblk * 64 + c];
#pragma unroll
            for (int m = 0; m < 4; ++m) {
                int r0 = rowblk * 64 + m * 16 + kg * 4;
#pragma unroll
                for (int j = 0; j < 4; ++j) {
                    int row = r0 + j;
                    if (row < M)
                        Cb[(size_t)row * 512 + colblk * 64 + c] = bf16_rne(acc[m][n][j] + bv);
                }
            }
        }
    } else {
#pragma unroll
        for (int n = 0; n < 4; ++n) {
            int c   = n * 16 + l15;
            int k_g = colblk * 64 + c;       // global k of next GEMM
            int kt_n = k_g >> 5, kk = k_g & 31, kgn = kk >> 3, kj = kk & 7;
            float bv = bias[k_g];
#pragma unroll
            for (int m = 0; m < 4; ++m) {
#pragma unroll
                for (int j = 0; j < 4; ++j) {
                    int rl  = m * 16 + kg * 4 + j;
                    int row = rowblk * 64 + rl;
                    float v = (row < M) ? fmaxf(acc[m][n][j] + bv, 0.f) : 0.f;
                    unsigned short h = bf16_rne(v);
                    unsigned short l = bf16_rne(v - bf16_to_f32(h));
                    size_t dst = (size_t)(rowblk * 16 + kt_n) * 4096 + rl * 32
                               + ((kgn ^ ((rl >> 1) & 3)) << 3) + kj;
                    Cpk[dst]        = (short)h;
                    Cpk[dst + 2048] = (short)l;
                }
            }
        }
    }
}

// ---------------- aggregation over bf16 H (unchanged, verified) ----------------

__global__ __launch_bounds__(256) void aggregate_bf16_kernel(
    const unsigned short* __restrict__ Hb,
    const float* __restrict__ dis,
    const int* __restrict__ row_off,
    const int* __restrict__ csr_src,
    const float* __restrict__ csr_norm,
    float* __restrict__ out)
{
    const int node = blockIdx.x;
    const int t = threadIdx.x;
    const int start = row_off[node];
    const int end   = row_off[node + 1];
    const float dn = dis[node];
    const float sw = dn * dn;

    ushort2 hv = *((const ushort2*)(Hb + (size_t)node * DIM) + t);
    float a0 = bf16_to_f32(hv.x) * sw;
    float a1 = bf16_to_f32(hv.y) * sw;

    int e = start;
    for (; e + 3 < end; e += 4) {
        int s0 = csr_src[e],     s1 = csr_src[e + 1];
        int s2 = csr_src[e + 2], s3 = csr_src[e + 3];
        float w0 = csr_norm[e],     w1 = csr_norm[e + 1];
        float w2 = csr_norm[e + 2], w3 = csr_norm[e + 3];
        ushort2 v0 = *((const ushort2*)(Hb + (size_t)s0 * DIM) + t);
        ushort2 v1 = *((const ushort2*)(Hb + (size_t)s1 * DIM) + t);
        ushort2 v2 = *((const ushort2*)(Hb + (size_t)s2 * DIM) + t);
        ushort2 v3 = *((const ushort2*)(Hb + (size_t)s3 * DIM) + t);
        a0 += bf16_to_f32(v0.x) * w0 + bf16_to_f32(v1.x) * w1
            + bf16_to_f32(v2.x) * w2 + bf16_to_f32(v3.x) * w3;
        a1 += bf16_to_f32(v0.y) * w0 + bf16_to_f32(v1.y) * w1
            + bf16_to_f32(v2.y) * w2 + bf16_to_f32(v3.y) * w3;
    }
    for (; e < end; ++e) {
        int s = csr_src[e];
        float w = csr_norm[e];
        ushort2 v = *((const ushort2*)(Hb + (size_t)s * DIM) + t);
        a0 += bf16_to_f32(v.x) * w;
        a1 += bf16_to_f32(v.y) * w;
    }
    float2 r = make_float2(a0, a1);
    *((float2*)(out + (size_t)node * DIM) + t) = r;
}

// ---------------- launch ----------------

extern "C" void kernel_launch(void* const* d_in, const int* in_sizes, int n_in,
                              void* d_out, int out_size, void* d_ws, size_t ws_size,
                              hipStream_t stream) {
    const float* x   = (const float*)d_in[0];
    const int*   ei  = (const int*)d_in[1];
    const float* W1  = (const float*)d_in[2];
    const float* b1  = (const float*)d_in[3];
    const float* W2  = (const float*)d_in[4];
    const float* b2  = (const float*)d_in[5];
    const float* Wp1 = (const float*)d_in[6];
    const float* bp1 = (const float*)d_in[7];
    const float* Wp2 = (const float*)d_in[8];
    const float* bp2 = (const float*)d_in[9];

    float* out  = (float*)d_out;
    float* z    = out + (size_t)N_NODES * DIM;
    float* proj = z   + (size_t)N_NODES * DIM;

    char* ws = (char*)d_ws;
    size_t off = 0;
    auto walloc = [&](size_t bytes) -> void* {
        void* p = ws + off;
        off = (off + bytes + 255) & ~(size_t)255;
        return p;
    };
    const size_t PK_SHORTS = (size_t)RBLKS * 16 * 4096;
    unsigned short* Hb = (unsigned short*)walloc((size_t)N_NODES * DIM * sizeof(unsigned short));
    short* APK0 = (short*)walloc(PK_SHORTS * sizeof(short));
    short* ZPKp = (short*)walloc(PK_SHORTS * sizeof(short));
    short* ZPKr = (short*)walloc(PK_SHORTS * sizeof(short));
    short* WT1  = (short*)walloc((size_t)8 * 16 * 4096 * sizeof(short));
    short* WT2  = (short*)walloc((size_t)8 * 16 * 4096 * sizeof(short));
    short* WTp1 = (short*)walloc((size_t)8 * 16 * 4096 * sizeof(short));
    short* WTp2 = (short*)walloc((size_t)8 * 16 * 4096 * sizeof(short));
    int*   deg      = (int*)  walloc(N_NODES * sizeof(int));
    int*   cursor   = (int*)  walloc(N_NODES * sizeof(int));
    int*   row_off  = (int*)  walloc((N_NODES + 1) * sizeof(int));
    int*   bsum     = (int*)  walloc(SCAN_BLKS * sizeof(int));
    float* dis      = (float*)walloc(N_NODES * sizeof(float));
    int*   csr_src  = (int*)  walloc(N_EDGES * sizeof(int));
    float* csr_norm = (float*)walloc(N_EDGES * sizeof(float));

    const dim3 blk(256);
    const dim3 gN(SCAN_BLKS);
    const dim3 gE((N_EDGES + 255) / 256);
    const dim3 pk_grid(16, RBLKS);
    const dim3 gemm_grid(8 * RBLKS);
    const dim3 wave(64);

    pack_weights4_kernel<<<512, blk, 0, stream>>>(W1, W2, Wp1, Wp2, WT1, WT2, WTp1, WTp2);
    pack_a_kernel<false><<<pk_grid, blk, 0, stream>>>(x, APK0, nullptr, N_NODES);

    zero_int_kernel<<<gN, blk, 0, stream>>>(deg, N_NODES);
    count_deg_kernel<<<gE, blk, 0, stream>>>(ei, deg, N_EDGES);
    scan1_kernel<<<gN, blk, 0, stream>>>(deg, row_off, bsum, dis, cursor, N_NODES);
    scan2_kernel<<<1, wave, 0, stream>>>(bsum);
    scan3_kernel<<<gN, blk, 0, stream>>>(row_off, bsum, N_NODES);
    scatter_kernel<<<gE, blk, 0, stream>>>(ei, dis, row_off, cursor, csr_src, csr_norm, N_EDGES);

    // z = aggregate(x @ W1 + b1)
    mfma_gemm64_kernel<2><<<gemm_grid, wave, 0, stream>>>(APK0, WT1, b1, nullptr, nullptr, Hb, N_NODES);
    aggregate_bf16_kernel<<<N_NODES, blk, 0, stream>>>(Hb, dis, row_off, csr_src, csr_norm, z);

    // pack z (plain + relu)
    pack_a_kernel<true><<<pk_grid, blk, 0, stream>>>(z, ZPKp, ZPKr, N_NODES);

    // out = aggregate(relu(z) @ W2 + b2)
    mfma_gemm64_kernel<2><<<gemm_grid, wave, 0, stream>>>(ZPKr, WT2, b2, nullptr, nullptr, Hb, N_NODES);
    aggregate_bf16_kernel<<<N_NODES, blk, 0, stream>>>(Hb, dis, row_off, csr_src, csr_norm, out);

    // P1 = relu(z @ Wp1 + bp1), written packed; proj = P1 @ Wp2 + bp2
    mfma_gemm64_kernel<1><<<gemm_grid, wave, 0, stream>>>(ZPKp, WTp1, bp1, nullptr, APK0, nullptr, N_NODES);
    mfma_gemm64_kernel<0><<<gemm_grid, wave, 0, stream>>>(APK0, WTp2, bp2, proj, nullptr, nullptr, N_NODES);
}

// Round 8
// 239.518 us; speedup vs baseline: 1.5516x; 1.1153x over previous
//
#include <hip/hip_runtime.h>
#include <stddef.h>

#define N_NODES 10000
#define N_EDGES 160000
#define DIM     512
#define RBLKS   157   // ceil(10000/64)
#define SCAN_BLKS 40  // ceil(10000/256)

typedef short bf16x8 __attribute__((ext_vector_type(8)));
typedef float f32x4  __attribute__((ext_vector_type(4)));

__device__ inline unsigned short bf16_rne(float f) {
    unsigned u = __builtin_bit_cast(unsigned, f);
    u += 0x7FFF + ((u >> 16) & 1);
    return (unsigned short)(u >> 16);
}
__device__ inline float bf16_to_f32(unsigned short h) {
    unsigned u = ((unsigned)h) << 16;
    return __builtin_bit_cast(float, u);
}

// ---------------- graph preprocessing ----------------

__global__ void zero_int_kernel(int* __restrict__ p, int n) {
    int i = blockIdx.x * blockDim.x + threadIdx.x;
    if (i < n) p[i] = 0;
}

__global__ void count_deg_kernel(const int* __restrict__ ei, int* __restrict__ deg, int E) {
    int e = blockIdx.x * blockDim.x + threadIdx.x;
    if (e < E) atomicAdd(&deg[ei[E + e]], 1);
}

// block-local inclusive scan of deg; also computes dis and zeroes cursor
__global__ __launch_bounds__(256) void scan1_kernel(const int* __restrict__ deg,
                                                    int* __restrict__ row_off,
                                                    int* __restrict__ bsum,
                                                    float* __restrict__ dis,
                                                    int* __restrict__ cursor, int n) {
    __shared__ int sm[256];
    const int i = blockIdx.x * 256 + threadIdx.x;
    int v = (i < n) ? deg[i] : 0;
    if (i < n) {
        dis[i] = rsqrtf((float)(v + 1));   // +1 self-loop
        cursor[i] = 0;
    }
    sm[threadIdx.x] = v;
    __syncthreads();
    for (int off = 1; off < 256; off <<= 1) {
        int t = (threadIdx.x >= (unsigned)off) ? sm[threadIdx.x - off] : 0;
        __syncthreads();
        sm[threadIdx.x] += t;
        __syncthreads();
    }
    if (i < n) row_off[i + 1] = sm[threadIdx.x];          // local inclusive
    if (threadIdx.x == 255) bsum[blockIdx.x] = sm[255];
}

// wave-scan of the SCAN_BLKS block sums -> exclusive
__global__ __launch_bounds__(64) void scan2_kernel(int* __restrict__ bsum) {
    const int lane = threadIdx.x;
    int v0 = (lane < SCAN_BLKS) ? bsum[lane] : 0;
    int v = v0;
    for (int off = 1; off < 64; off <<= 1) {
        int t = __shfl_up(v, off, 64);
        if (lane >= off) v += t;
    }
    if (lane < SCAN_BLKS) bsum[lane] = v - v0;            // exclusive
}

__global__ __launch_bounds__(256) void scan3_kernel(int* __restrict__ row_off,
                                                    const int* __restrict__ bsum, int n) {
    const int i = blockIdx.x * 256 + threadIdx.x;
    if (i < n) row_off[i + 1] += bsum[blockIdx.x];
    if (i == 0) row_off[0] = 0;
}

__global__ void scatter_kernel(const int* __restrict__ ei, const float* __restrict__ dis,
                               const int* __restrict__ row_off, int* __restrict__ cursor,
                               int* __restrict__ csr_src, float* __restrict__ csr_norm, int E) {
    int e = blockIdx.x * blockDim.x + threadIdx.x;
    if (e >= E) return;
    int s = ei[e];
    int d = ei[E + e];
    int slot = row_off[d] + atomicAdd(&cursor[d], 1);
    csr_src[slot]  = s;
    csr_norm[slot] = dis[s] * dis[d];
}

// ---------------- packing ----------------
// Tile layout (shorts): [blk][kt 16][arr 2(hi/lo)][idx 64][k 32], tile = 4096 shorts.
// XOR permutation baked in: k-group kq stored at (kq ^ ((idx>>1)&3)) — a pure
// within-1KB permutation; GEMM reads with the same mapping.

__global__ __launch_bounds__(256) void pack_weights4_kernel(
    const float* __restrict__ W1, const float* __restrict__ W2,
    const float* __restrict__ Wp1, const float* __restrict__ Wp2,
    short* __restrict__ T1, short* __restrict__ T2,
    short* __restrict__ Tp1, short* __restrict__ Tp2) {
    const int wsel = blockIdx.x >> 7;
    const float* W = (wsel == 0) ? W1 : (wsel == 1) ? W2 : (wsel == 2) ? Wp1 : Wp2;
    short* WT      = (wsel == 0) ? T1 : (wsel == 1) ? T2 : (wsel == 2) ? Tp1 : Tp2;
    int id = (blockIdx.x & 127) * 256 + threadIdx.x;   // 32768 per weight
    int n  = id & 511;
    int kc = id >> 9;
    int colblk = n >> 6, col = n & 63;
    int kt = kc >> 2, kq = kc & 3;
    short hi[8], lo[8];
#pragma unroll
    for (int j = 0; j < 8; ++j) {
        float v = W[(size_t)(kc * 8 + j) * 512 + n];
        unsigned short h = bf16_rne(v);
        hi[j] = (short)h;
        lo[j] = (short)bf16_rne(v - bf16_to_f32(h));
    }
    size_t base = (size_t)(colblk * 16 + kt) * 4096 + col * 32 + ((kq ^ ((col >> 1) & 3)) << 3);
    *(int4*)(WT + base)        = *(const int4*)hi;
    *(int4*)(WT + base + 2048) = *(const int4*)lo;
}

template<bool DUAL>
__global__ __launch_bounds__(256) void pack_a_kernel(const float* __restrict__ A,
                                                     short* __restrict__ P0,
                                                     short* __restrict__ P1, int M) {
    const int kt = blockIdx.x;
    const int rb = blockIdx.y;
    const int t  = threadIdx.x;
    const int r  = t >> 2;
    const int kq = t & 3;
    const int row = rb * 64 + r;
    float v[8] = {};
    if (row < M) {
        float4 a = *(const float4*)(A + (size_t)row * 512 + kt * 32 + kq * 8);
        float4 b = *(const float4*)(A + (size_t)row * 512 + kt * 32 + kq * 8 + 4);
        v[0]=a.x; v[1]=a.y; v[2]=a.z; v[3]=a.w; v[4]=b.x; v[5]=b.y; v[6]=b.z; v[7]=b.w;
    }
    size_t base = (size_t)(rb * 16 + kt) * 4096 + r * 32 + ((kq ^ ((r >> 1) & 3)) << 3);
    short hi[8], lo[8];
#pragma unroll
    for (int j = 0; j < 8; ++j) {
        unsigned short h = bf16_rne(v[j]);
        hi[j] = (short)h;
        lo[j] = (short)bf16_rne(v[j] - bf16_to_f32(h));
    }
    *(int4*)(P0 + base)        = *(const int4*)hi;
    *(int4*)(P0 + base + 2048) = *(const int4*)lo;
    if (DUAL) {
#pragma unroll
        for (int j = 0; j < 8; ++j) {
            float rv = fmaxf(v[j], 0.f);
            unsigned short h = bf16_rne(rv);
            hi[j] = (short)h;
            lo[j] = (short)bf16_rne(rv - bf16_to_f32(h));
        }
        *(int4*)(P1 + base)        = *(const int4*)hi;
        *(int4*)(P1 + base + 2048) = *(const int4*)lo;
    }
}

// ---------------- split-K MFMA GEMM: 64x64 tile, 4 waves each own a K-quarter ----------------
// Operands pre-packed in per-lane fragment order (1KB coalesced segments). LDS only
// for the final cross-wave reduction. Wave 0 runs the epilogue.
// EPI 0: C = f32 (+bias), EPI 1: C packed bf16 hi/lo tiles (+bias, relu), EPI 2: C bf16 row-major (+bias)

template<int EPI>
__global__ __launch_bounds__(256) void mfma_gemm_splitk_kernel(
    const short* __restrict__ Apk, const short* __restrict__ Wpk,
    const float* __restrict__ bias,
    float* __restrict__ Cf, short* __restrict__ Cpk,
    unsigned short* __restrict__ Cb, int M)
{
    __shared__ f32x4 red[2][16][64];   // 32 KB, [q][lane] => conflict-free b128

    const int bid = blockIdx.x;            // 0..1255 (=8*RBLKS)
    const int lin = (bid & 7) * RBLKS + (bid >> 3);   // XCD-chunked swizzle
    const int rowblk = lin >> 3;
    const int colblk = lin & 7;

    const int tid  = threadIdx.x;
    const int wv   = tid >> 6;             // K-quarter 0..3
    const int lane = tid & 63;
    const int l15 = lane & 15;
    const int kg  = lane >> 4;
    const int kso = ((kg ^ ((l15 >> 1) & 3)) << 3);   // baked permutation (lane-const)

    const short* Ab = Apk + (size_t)rowblk * 16 * 4096;
    const short* Bb = Wpk + (size_t)colblk * 16 * 4096;

    f32x4 acc[4][4];
#pragma unroll
    for (int i = 0; i < 4; ++i)
#pragma unroll
        for (int j = 0; j < 4; ++j) acc[i][j] = (f32x4){0.f, 0.f, 0.f, 0.f};

#pragma unroll
    for (int i = 0; i < 4; ++i) {
        const int kt = wv * 4 + i;
        const short* ak = Ab + kt * 4096;
        const short* bk = Bb + kt * 4096;
        bf16x8 a[4][2], b[4][2];
#pragma unroll
        for (int m = 0; m < 4; ++m) {
            const int ro = (m * 16 + l15) * 32 + kso;
#pragma unroll
            for (int s = 0; s < 2; ++s) {
                a[m][s] = *(const bf16x8*)(ak + s * 2048 + ro);
                b[m][s] = *(const bf16x8*)(bk + s * 2048 + ro);
            }
        }
#pragma unroll
        for (int m = 0; m < 4; ++m)
#pragma unroll
            for (int n = 0; n < 4; ++n) {
                acc[m][n] = __builtin_amdgcn_mfma_f32_16x16x32_bf16(a[m][0], b[n][0], acc[m][n], 0, 0, 0);
                acc[m][n] = __builtin_amdgcn_mfma_f32_16x16x32_bf16(a[m][0], b[n][1], acc[m][n], 0, 0, 0);
                acc[m][n] = __builtin_amdgcn_mfma_f32_16x16x32_bf16(a[m][1], b[n][0], acc[m][n], 0, 0, 0);
            }
    }

    // cross-wave reduction: (w0+=w2's, w1+=w3's), then w0+=w1's
    if (wv >= 2) {
#pragma unroll
        for (int m = 0; m < 4; ++m)
#pragma unroll
            for (int n = 0; n < 4; ++n) red[wv - 2][m * 4 + n][lane] = acc[m][n];
    }
    __syncthreads();
    if (wv < 2) {
#pragma unroll
        for (int m = 0; m < 4; ++m)
#pragma unroll
            for (int n = 0; n < 4; ++n) acc[m][n] += red[wv][m * 4 + n][lane];
    }
    __syncthreads();
    if (wv == 1) {
#pragma unroll
        for (int m = 0; m < 4; ++m)
#pragma unroll
            for (int n = 0; n < 4; ++n) red[0][m * 4 + n][lane] = acc[m][n];
    }
    __syncthreads();
    if (wv != 0) return;
#pragma unroll
    for (int m = 0; m < 4; ++m)
#pragma unroll
        for (int n = 0; n < 4; ++n) acc[m][n] += red[0][m * 4 + n][lane];

    if (EPI == 0) {
#pragma unroll
        for (int n = 0; n < 4; ++n) {
            int c = n * 16 + l15;
            float bv = bias[colblk * 64 + c];
#pragma unroll
            for (int m = 0; m < 4; ++m) {
                int r0 = rowblk * 64 + m * 16 + kg * 4;
#pragma unroll
                for (int j = 0; j < 4; ++j) {
                    int row = r0 + j;
                    if (row < M)
                        Cf[(size_t)row * 512 + colblk * 64 + c] = acc[m][n][j] + bv;
                }
            }
        }
    } else if (EPI == 2) {
#pragma unroll
        for (int n = 0; n < 4; ++n) {
            int c = n * 16 + l15;
            float bv = bias[colblk * 64 + c];
#pragma unroll
            for (int m = 0; m < 4; ++m) {
                int r0 = rowblk * 64 + m * 16 + kg * 4;
#pragma unroll
                for (int j = 0; j < 4; ++j) {
                    int row = r0 + j;
                    if (row < M)
                        Cb[(size_t)row * 512 + colblk * 64 + c] = bf16_rne(acc[m][n][j] + bv);
                }
            }
        }
    } else {
#pragma unroll
        for (int n = 0; n < 4; ++n) {
            int c   = n * 16 + l15;
            int k_g = colblk * 64 + c;       // global k of next GEMM
            int kt_n = k_g >> 5, kk = k_g & 31, kgn = kk >> 3, kj = kk & 7;
            float bv = bias[k_g];
#pragma unroll
            for (int m = 0; m < 4; ++m) {
#pragma unroll
                for (int j = 0; j < 4; ++j) {
                    int rl  = m * 16 + kg * 4 + j;
                    int row = rowblk * 64 + rl;
                    float v = (row < M) ? fmaxf(acc[m][n][j] + bv, 0.f) : 0.f;
                    unsigned short h = bf16_rne(v);
                    unsigned short l = bf16_rne(v - bf16_to_f32(h));
                    size_t dst = (size_t)(rowblk * 16 + kt_n) * 4096 + rl * 32
                               + ((kgn ^ ((rl >> 1) & 3)) << 3) + kj;
                    Cpk[dst]        = (short)h;
                    Cpk[dst + 2048] = (short)l;
                }
            }
        }
    }
}

// ---------------- aggregation over bf16 H (unchanged, verified) ----------------

__global__ __launch_bounds__(256) void aggregate_bf16_kernel(
    const unsigned short* __restrict__ Hb,
    const float* __restrict__ dis,
    const int* __restrict__ row_off,
    const int* __restrict__ csr_src,
    const float* __restrict__ csr_norm,
    float* __restrict__ out)
{
    const int node = blockIdx.x;
    const int t = threadIdx.x;
    const int start = row_off[node];
    const int end   = row_off[node + 1];
    const float dn = dis[node];
    const float sw = dn * dn;

    ushort2 hv = *((const ushort2*)(Hb + (size_t)node * DIM) + t);
    float a0 = bf16_to_f32(hv.x) * sw;
    float a1 = bf16_to_f32(hv.y) * sw;

    int e = start;
    for (; e + 3 < end; e += 4) {
        int s0 = csr_src[e],     s1 = csr_src[e + 1];
        int s2 = csr_src[e + 2], s3 = csr_src[e + 3];
        float w0 = csr_norm[e],     w1 = csr_norm[e + 1];
        float w2 = csr_norm[e + 2], w3 = csr_norm[e + 3];
        ushort2 v0 = *((const ushort2*)(Hb + (size_t)s0 * DIM) + t);
        ushort2 v1 = *((const ushort2*)(Hb + (size_t)s1 * DIM) + t);
        ushort2 v2 = *((const ushort2*)(Hb + (size_t)s2 * DIM) + t);
        ushort2 v3 = *((const ushort2*)(Hb + (size_t)s3 * DIM) + t);
        a0 += bf16_to_f32(v0.x) * w0 + bf16_to_f32(v1.x) * w1
            + bf16_to_f32(v2.x) * w2 + bf16_to_f32(v3.x) * w3;
        a1 += bf16_to_f32(v0.y) * w0 + bf16_to_f32(v1.y) * w1
            + bf16_to_f32(v2.y) * w2 + bf16_to_f32(v3.y) * w3;
    }
    for (; e < end; ++e) {
        int s = csr_src[e];
        float w = csr_norm[e];
        ushort2 v = *((const ushort2*)(Hb + (size_t)s * DIM) + t);
        a0 += bf16_to_f32(v.x) * w;
        a1 += bf16_to_f32(v.y) * w;
    }
    float2 r = make_float2(a0, a1);
    *((float2*)(out + (size_t)node * DIM) + t) = r;
}

// ---------------- launch ----------------

extern "C" void kernel_launch(void* const* d_in, const int* in_sizes, int n_in,
                              void* d_out, int out_size, void* d_ws, size_t ws_size,
                              hipStream_t stream) {
    const float* x   = (const float*)d_in[0];
    const int*   ei  = (const int*)d_in[1];
    const float* W1  = (const float*)d_in[2];
    const float* b1  = (const float*)d_in[3];
    const float* W2  = (const float*)d_in[4];
    const float* b2  = (const float*)d_in[5];
    const float* Wp1 = (const float*)d_in[6];
    const float* bp1 = (const float*)d_in[7];
    const float* Wp2 = (const float*)d_in[8];
    const float* bp2 = (const float*)d_in[9];

    float* out  = (float*)d_out;
    float* z    = out + (size_t)N_NODES * DIM;
    float* proj = z   + (size_t)N_NODES * DIM;

    char* ws = (char*)d_ws;
    size_t off = 0;
    auto walloc = [&](size_t bytes) -> void* {
        void* p = ws + off;
        off = (off + bytes + 255) & ~(size_t)255;
        return p;
    };
    const size_t PK_SHORTS = (size_t)RBLKS * 16 * 4096;
    unsigned short* Hb = (unsigned short*)walloc((size_t)N_NODES * DIM * sizeof(unsigned short));
    short* APK0 = (short*)walloc(PK_SHORTS * sizeof(short));
    short* ZPKp = (short*)walloc(PK_SHORTS * sizeof(short));
    short* ZPKr = (short*)walloc(PK_SHORTS * sizeof(short));
    short* WT1  = (short*)walloc((size_t)8 * 16 * 4096 * sizeof(short));
    short* WT2  = (short*)walloc((size_t)8 * 16 * 4096 * sizeof(short));
    short* WTp1 = (short*)walloc((size_t)8 * 16 * 4096 * sizeof(short));
    short* WTp2 = (short*)walloc((size_t)8 * 16 * 4096 * sizeof(short));
    int*   deg      = (int*)  walloc(N_NODES * sizeof(int));
    int*   cursor   = (int*)  walloc(N_NODES * sizeof(int));
    int*   row_off  = (int*)  walloc((N_NODES + 1) * sizeof(int));
    int*   bsum     = (int*)  walloc(SCAN_BLKS * sizeof(int));
    float* dis      = (float*)walloc(N_NODES * sizeof(float));
    int*   csr_src  = (int*)  walloc(N_EDGES * sizeof(int));
    float* csr_norm = (float*)walloc(N_EDGES * sizeof(float));

    const dim3 blk(256);
    const dim3 gN(SCAN_BLKS);
    const dim3 gE((N_EDGES + 255) / 256);
    const dim3 pk_grid(16, RBLKS);
    const dim3 gemm_grid(8 * RBLKS);
    const dim3 wave(64);

    pack_weights4_kernel<<<512, blk, 0, stream>>>(W1, W2, Wp1, Wp2, WT1, WT2, WTp1, WTp2);
    pack_a_kernel<false><<<pk_grid, blk, 0, stream>>>(x, APK0, nullptr, N_NODES);

    zero_int_kernel<<<gN, blk, 0, stream>>>(deg, N_NODES);
    count_deg_kernel<<<gE, blk, 0, stream>>>(ei, deg, N_EDGES);
    scan1_kernel<<<gN, blk, 0, stream>>>(deg, row_off, bsum, dis, cursor, N_NODES);
    scan2_kernel<<<1, wave, 0, stream>>>(bsum);
    scan3_kernel<<<gN, blk, 0, stream>>>(row_off, bsum, N_NODES);
    scatter_kernel<<<gE, blk, 0, stream>>>(ei, dis, row_off, cursor, csr_src, csr_norm, N_EDGES);

    // z = aggregate(x @ W1 + b1)
    mfma_gemm_splitk_kernel<2><<<gemm_grid, blk, 0, stream>>>(APK0, WT1, b1, nullptr, nullptr, Hb, N_NODES);
    aggregate_bf16_kernel<<<N_NODES, blk, 0, stream>>>(Hb, dis, row_off, csr_src, csr_norm, z);

    // pack z (plain + relu)
    pack_a_kernel<true><<<pk_grid, blk, 0, stream>>>(z, ZPKp, ZPKr, N_NODES);

    // out = aggregate(relu(z) @ W2 + b2)
    mfma_gemm_splitk_kernel<2><<<gemm_grid, blk, 0, stream>>>(ZPKr, WT2, b2, nullptr, nullptr, Hb, N_NODES);
    aggregate_bf16_kernel<<<N_NODES, blk, 0, stream>>>(Hb, dis, row_off, csr_src, csr_norm, out);

    // P1 = relu(z @ Wp1 + bp1), written packed; proj = P1 @ Wp2 + bp2
    mfma_gemm_splitk_kernel<1><<<gemm_grid, blk, 0, stream>>>(ZPKp, WTp1, bp1, nullptr, APK0, nullptr, N_NODES);
    mfma_gemm_splitk_kernel<0><<<gemm_grid, blk, 0, stream>>>(APK0, WTp2, bp2, proj, nullptr, nullptr, N_NODES);
}

// Round 9
// 229.341 us; speedup vs baseline: 1.6205x; 1.0444x over previous
//
#include <hip/hip_runtime.h>
#include <stddef.h>

#define N_NODES 10000
#define N_EDGES 160000
#define DIM     512
#define RBLKS   157   // ceil(10000/64)
#define GBLKS   (8 * RBLKS)   // 1256 gemm blocks
#define SCAN_BLKS 40  // ceil(10000/256)

typedef short bf16x8 __attribute__((ext_vector_type(8)));
typedef float f32x4  __attribute__((ext_vector_type(4)));

__device__ inline unsigned short bf16_rne(float f) {
    unsigned u = __builtin_bit_cast(unsigned, f);
    u += 0x7FFF + ((u >> 16) & 1);
    return (unsigned short)(u >> 16);
}
__device__ inline float bf16_to_f32(unsigned short h) {
    unsigned u = ((unsigned)h) << 16;
    return __builtin_bit_cast(float, u);
}

// ================= fused pack_weights + zero_deg =================
// blocks [0,512): pack 4 weights; blocks [512,552): zero deg

__global__ __launch_bounds__(256) void packw_zero_kernel(
    const float* __restrict__ W1, const float* __restrict__ W2,
    const float* __restrict__ Wp1, const float* __restrict__ Wp2,
    short* __restrict__ T1, short* __restrict__ T2,
    short* __restrict__ Tp1, short* __restrict__ Tp2,
    int* __restrict__ deg) {
    const int bid = blockIdx.x;
    if (bid >= 512) {
        int i = (bid - 512) * 256 + threadIdx.x;
        if (i < N_NODES) deg[i] = 0;
        return;
    }
    const int wsel = bid >> 7;
    const float* W = (wsel == 0) ? W1 : (wsel == 1) ? W2 : (wsel == 2) ? Wp1 : Wp2;
    short* WT      = (wsel == 0) ? T1 : (wsel == 1) ? T2 : (wsel == 2) ? Tp1 : Tp2;
    int id = (bid & 127) * 256 + threadIdx.x;
    int n  = id & 511;
    int kc = id >> 9;
    int colblk = n >> 6, col = n & 63;
    int kt = kc >> 2, kq = kc & 3;
    short hi[8], lo[8];
#pragma unroll
    for (int j = 0; j < 8; ++j) {
        float v = W[(size_t)(kc * 8 + j) * 512 + n];
        unsigned short h = bf16_rne(v);
        hi[j] = (short)h;
        lo[j] = (short)bf16_rne(v - bf16_to_f32(h));
    }
    size_t base = (size_t)(colblk * 16 + kt) * 4096 + col * 32 + ((kq ^ ((col >> 1) & 3)) << 3);
    *(int4*)(WT + base)        = *(const int4*)hi;
    *(int4*)(WT + base + 2048) = *(const int4*)lo;
}

// ================= fused pack_a(x) + count_deg =================
// blocks [0,2512): pack x (kt=bid&15, rb=bid>>4); blocks [2512,3137): count deg

__global__ __launch_bounds__(256) void packa_count_kernel(
    const float* __restrict__ A, short* __restrict__ P0,
    const int* __restrict__ ei, int* __restrict__ deg) {
    const int bid = blockIdx.x;
    if (bid >= 2512) {
        int e = (bid - 2512) * 256 + threadIdx.x;
        if (e < N_EDGES) atomicAdd(&deg[ei[N_EDGES + e]], 1);
        return;
    }
    const int kt = bid & 15;
    const int rb = bid >> 4;
    const int t  = threadIdx.x;
    const int r  = t >> 2;
    const int kq = t & 3;
    const int row = rb * 64 + r;
    float v[8] = {};
    if (row < N_NODES) {
        float4 a = *(const float4*)(A + (size_t)row * 512 + kt * 32 + kq * 8);
        float4 b = *(const float4*)(A + (size_t)row * 512 + kt * 32 + kq * 8 + 4);
        v[0]=a.x; v[1]=a.y; v[2]=a.z; v[3]=a.w; v[4]=b.x; v[5]=b.y; v[6]=b.z; v[7]=b.w;
    }
    size_t base = (size_t)(rb * 16 + kt) * 4096 + r * 32 + ((kq ^ ((r >> 1) & 3)) << 3);
    short hi[8], lo[8];
#pragma unroll
    for (int j = 0; j < 8; ++j) {
        unsigned short h = bf16_rne(v[j]);
        hi[j] = (short)h;
        lo[j] = (short)bf16_rne(v[j] - bf16_to_f32(h));
    }
    *(int4*)(P0 + base)        = *(const int4*)hi;
    *(int4*)(P0 + base + 2048) = *(const int4*)lo;
}

// ================= scans (verified) =================

__global__ __launch_bounds__(256) void scan1_kernel(const int* __restrict__ deg,
                                                    int* __restrict__ row_off,
                                                    int* __restrict__ bsum,
                                                    float* __restrict__ dis,
                                                    int* __restrict__ cursor, int n) {
    __shared__ int sm[256];
    const int i = blockIdx.x * 256 + threadIdx.x;
    int v = (i < n) ? deg[i] : 0;
    if (i < n) {
        dis[i] = rsqrtf((float)(v + 1));
        cursor[i] = 0;
    }
    sm[threadIdx.x] = v;
    __syncthreads();
    for (int off = 1; off < 256; off <<= 1) {
        int t = (threadIdx.x >= (unsigned)off) ? sm[threadIdx.x - off] : 0;
        __syncthreads();
        sm[threadIdx.x] += t;
        __syncthreads();
    }
    if (i < n) row_off[i + 1] = sm[threadIdx.x];
    if (threadIdx.x == 255) bsum[blockIdx.x] = sm[255];
}

__global__ __launch_bounds__(64) void scan2_kernel(int* __restrict__ bsum) {
    const int lane = threadIdx.x;
    int v0 = (lane < SCAN_BLKS) ? bsum[lane] : 0;
    int v = v0;
    for (int off = 1; off < 64; off <<= 1) {
        int t = __shfl_up(v, off, 64);
        if (lane >= off) v += t;
    }
    if (lane < SCAN_BLKS) bsum[lane] = v - v0;
}

__global__ __launch_bounds__(256) void scan3_kernel(int* __restrict__ row_off,
                                                    const int* __restrict__ bsum, int n) {
    const int i = blockIdx.x * 256 + threadIdx.x;
    if (i < n) row_off[i + 1] += bsum[blockIdx.x];
    if (i == 0) row_off[0] = 0;
}

// ================= split-K GEMM core (device) =================
// 64x64 tile, 4 waves own K-quarters, operands pre-packed per-lane fragment order.

__device__ __forceinline__ bool gemm_splitk_core(
    const short* __restrict__ Apk, const short* __restrict__ Wpk,
    int bid, f32x4 (&acc)[4][4], f32x4 (*red)[16][64],
    int& rowblk, int& colblk)
{
    const int lin = (bid & 7) * RBLKS + (bid >> 3);   // XCD-chunked swizzle
    rowblk = lin >> 3;
    colblk = lin & 7;

    const int tid  = threadIdx.x;
    const int wv   = tid >> 6;
    const int lane = tid & 63;
    const int l15 = lane & 15;
    const int kg  = lane >> 4;
    const int kso = ((kg ^ ((l15 >> 1) & 3)) << 3);

    const short* Ab = Apk + (size_t)rowblk * 16 * 4096;
    const short* Bb = Wpk + (size_t)colblk * 16 * 4096;

#pragma unroll
    for (int i = 0; i < 4; ++i)
#pragma unroll
        for (int j = 0; j < 4; ++j) acc[i][j] = (f32x4){0.f, 0.f, 0.f, 0.f};

#pragma unroll
    for (int i = 0; i < 4; ++i) {
        const int kt = wv * 4 + i;
        const short* ak = Ab + kt * 4096;
        const short* bk = Bb + kt * 4096;
        bf16x8 a[4][2], b[4][2];
#pragma unroll
        for (int m = 0; m < 4; ++m) {
            const int ro = (m * 16 + l15) * 32 + kso;
#pragma unroll
            for (int s = 0; s < 2; ++s) {
                a[m][s] = *(const bf16x8*)(ak + s * 2048 + ro);
                b[m][s] = *(const bf16x8*)(bk + s * 2048 + ro);
            }
        }
#pragma unroll
        for (int m = 0; m < 4; ++m)
#pragma unroll
            for (int n = 0; n < 4; ++n) {
                acc[m][n] = __builtin_amdgcn_mfma_f32_16x16x32_bf16(a[m][0], b[n][0], acc[m][n], 0, 0, 0);
                acc[m][n] = __builtin_amdgcn_mfma_f32_16x16x32_bf16(a[m][0], b[n][1], acc[m][n], 0, 0, 0);
                acc[m][n] = __builtin_amdgcn_mfma_f32_16x16x32_bf16(a[m][1], b[n][0], acc[m][n], 0, 0, 0);
            }
    }

    if (wv >= 2) {
#pragma unroll
        for (int m = 0; m < 4; ++m)
#pragma unroll
            for (int n = 0; n < 4; ++n) red[wv - 2][m * 4 + n][lane] = acc[m][n];
    }
    __syncthreads();
    if (wv < 2) {
#pragma unroll
        for (int m = 0; m < 4; ++m)
#pragma unroll
            for (int n = 0; n < 4; ++n) acc[m][n] += red[wv][m * 4 + n][lane];
    }
    __syncthreads();
    if (wv == 1) {
#pragma unroll
        for (int m = 0; m < 4; ++m)
#pragma unroll
            for (int n = 0; n < 4; ++n) red[0][m * 4 + n][lane] = acc[m][n];
    }
    __syncthreads();
    if (wv != 0) return false;
#pragma unroll
    for (int m = 0; m < 4; ++m)
#pragma unroll
        for (int n = 0; n < 4; ++n) acc[m][n] += red[0][m * 4 + n][lane];
    return true;
}

// ---- epilogue helpers (wave 0 only) ----

__device__ __forceinline__ void epi_f32(f32x4 (&acc)[4][4], const float* bias,
                                        float* Cf, int rowblk, int colblk) {
    const int lane = threadIdx.x & 63;
    const int l15 = lane & 15, kg = lane >> 4;
#pragma unroll
    for (int n = 0; n < 4; ++n) {
        int c = n * 16 + l15;
        float bv = bias[colblk * 64 + c];
#pragma unroll
        for (int m = 0; m < 4; ++m) {
            int r0 = rowblk * 64 + m * 16 + kg * 4;
#pragma unroll
            for (int j = 0; j < 4; ++j) {
                int row = r0 + j;
                if (row < N_NODES)
                    Cf[(size_t)row * 512 + colblk * 64 + c] = acc[m][n][j] + bv;
            }
        }
    }
}

__device__ __forceinline__ void epi_bf16(f32x4 (&acc)[4][4], const float* bias,
                                         unsigned short* Cb, int rowblk, int colblk) {
    const int lane = threadIdx.x & 63;
    const int l15 = lane & 15, kg = lane >> 4;
#pragma unroll
    for (int n = 0; n < 4; ++n) {
        int c = n * 16 + l15;
        float bv = bias[colblk * 64 + c];
#pragma unroll
        for (int m = 0; m < 4; ++m) {
            int r0 = rowblk * 64 + m * 16 + kg * 4;
#pragma unroll
            for (int j = 0; j < 4; ++j) {
                int row = r0 + j;
                if (row < N_NODES)
                    Cb[(size_t)row * 512 + colblk * 64 + c] = bf16_rne(acc[m][n][j] + bv);
            }
        }
    }
}

__device__ __forceinline__ void epi_pack(f32x4 (&acc)[4][4], const float* bias,
                                         short* Cpk, int rowblk, int colblk) {
    const int lane = threadIdx.x & 63;
    const int l15 = lane & 15, kg = lane >> 4;
#pragma unroll
    for (int n = 0; n < 4; ++n) {
        int c   = n * 16 + l15;
        int k_g = colblk * 64 + c;
        int kt_n = k_g >> 5, kk = k_g & 31, kgn = kk >> 3, kj = kk & 7;
        float bv = bias[k_g];
#pragma unroll
        for (int m = 0; m < 4; ++m) {
#pragma unroll
            for (int j = 0; j < 4; ++j) {
                int rl  = m * 16 + kg * 4 + j;
                int row = rowblk * 64 + rl;
                float v = (row < N_NODES) ? fmaxf(acc[m][n][j] + bv, 0.f) : 0.f;
                unsigned short h = bf16_rne(v);
                unsigned short l = bf16_rne(v - bf16_to_f32(h));
                size_t dst = (size_t)(rowblk * 16 + kt_n) * 4096 + rl * 32
                           + ((kgn ^ ((rl >> 1) & 3)) << 3) + kj;
                Cpk[dst]        = (short)h;
                Cpk[dst + 2048] = (short)l;
            }
        }
    }
}

// ================= fused GEMM1 + scatter =================
// blocks [0,GBLKS): GEMM1 (APKx @ WT1 + b1 -> Hb bf16); [GBLKS, GBLKS+625): scatter

__global__ __launch_bounds__(256) void gemm1_scatter_kernel(
    const short* __restrict__ Apk, const short* __restrict__ Wpk,
    const float* __restrict__ bias, unsigned short* __restrict__ Hb,
    const int* __restrict__ ei, const float* __restrict__ dis,
    const int* __restrict__ row_off, int* __restrict__ cursor,
    int* __restrict__ csr_src, float* __restrict__ csr_norm)
{
    __shared__ f32x4 red[2][16][64];
    const int bid = blockIdx.x;
    if (bid >= GBLKS) {
        int e = (bid - GBLKS) * 256 + threadIdx.x;
        if (e < N_EDGES) {
            int s = ei[e];
            int d = ei[N_EDGES + e];
            int slot = row_off[d] + atomicAdd(&cursor[d], 1);
            csr_src[slot]  = s;
            csr_norm[slot] = dis[s] * dis[d];
        }
        return;
    }
    f32x4 acc[4][4];
    int rowblk, colblk;
    if (gemm_splitk_core(Apk, Wpk, bid, acc, red, rowblk, colblk))
        epi_bf16(acc, bias, Hb, rowblk, colblk);
}

// ================= aggregate1 + fused z-pack =================
// z = gather(Hb); also writes ZPKp (packed z) and ZPKr (packed relu z)

__global__ __launch_bounds__(256) void agg1_pack_kernel(
    const unsigned short* __restrict__ Hb,
    const float* __restrict__ dis,
    const int* __restrict__ row_off,
    const int* __restrict__ csr_src,
    const float* __restrict__ csr_norm,
    float* __restrict__ z,
    short* __restrict__ ZPKp, short* __restrict__ ZPKr)
{
    const int node = blockIdx.x;
    const int t = threadIdx.x;
    const int start = row_off[node];
    const int end   = row_off[node + 1];
    const float dn = dis[node];
    const float sw = dn * dn;

    ushort2 hv = *((const ushort2*)(Hb + (size_t)node * DIM) + t);
    float a0 = bf16_to_f32(hv.x) * sw;
    float a1 = bf16_to_f32(hv.y) * sw;

    int e = start;
    for (; e + 3 < end; e += 4) {
        int s0 = csr_src[e],     s1 = csr_src[e + 1];
        int s2 = csr_src[e + 2], s3 = csr_src[e + 3];
        float w0 = csr_norm[e],     w1 = csr_norm[e + 1];
        float w2 = csr_norm[e + 2], w3 = csr_norm[e + 3];
        ushort2 v0 = *((const ushort2*)(Hb + (size_t)s0 * DIM) + t);
        ushort2 v1 = *((const ushort2*)(Hb + (size_t)s1 * DIM) + t);
        ushort2 v2 = *((const ushort2*)(Hb + (size_t)s2 * DIM) + t);
        ushort2 v3 = *((const ushort2*)(Hb + (size_t)s3 * DIM) + t);
        a0 += bf16_to_f32(v0.x) * w0 + bf16_to_f32(v1.x) * w1
            + bf16_to_f32(v2.x) * w2 + bf16_to_f32(v3.x) * w3;
        a1 += bf16_to_f32(v0.y) * w0 + bf16_to_f32(v1.y) * w1
            + bf16_to_f32(v2.y) * w2 + bf16_to_f32(v3.y) * w3;
    }
    for (; e < end; ++e) {
        int s = csr_src[e];
        float w = csr_norm[e];
        ushort2 v = *((const ushort2*)(Hb + (size_t)s * DIM) + t);
        a0 += bf16_to_f32(v.x) * w;
        a1 += bf16_to_f32(v.y) * w;
    }
    *((float2*)(z + (size_t)node * DIM) + t) = make_float2(a0, a1);

    // fused pack: element (node, f) -> (rb*16+kt)*4096 + r*32 + ((kq^((r>>1)&3))<<3) + j
    const int f0 = 2 * t;
    const int kt = f0 >> 5, kq = (f0 >> 3) & 3, j = f0 & 7;
    const int rb = node >> 6, r = node & 63;
    const size_t dst = (size_t)(rb * 16 + kt) * 4096 + r * 32 + ((kq ^ ((r >> 1) & 3)) << 3) + j;

    unsigned short h0 = bf16_rne(a0), h1 = bf16_rne(a1);
    *(ushort2*)(ZPKp + dst)        = make_ushort2(h0, h1);
    *(ushort2*)(ZPKp + dst + 2048) = make_ushort2(bf16_rne(a0 - bf16_to_f32(h0)),
                                                  bf16_rne(a1 - bf16_to_f32(h1)));
    float r0 = fmaxf(a0, 0.f), r1 = fmaxf(a1, 0.f);
    unsigned short g0 = bf16_rne(r0), g1 = bf16_rne(r1);
    *(ushort2*)(ZPKr + dst)        = make_ushort2(g0, g1);
    *(ushort2*)(ZPKr + dst + 2048) = make_ushort2(bf16_rne(r0 - bf16_to_f32(g0)),
                                                  bf16_rne(r1 - bf16_to_f32(g1)));
}

// ================= fused GEMM2 || GEMM3 =================
// blocks [0,GBLKS): ZPKr@WT2+b2 -> Hb (bf16); [GBLKS,2*GBLKS): ZPKp@WTp1+bp1 -> APK (packed,relu)

__global__ __launch_bounds__(256) void gemm23_kernel(
    const short* __restrict__ ZPKr, const short* __restrict__ WT2,
    const float* __restrict__ b2, unsigned short* __restrict__ Hb,
    const short* __restrict__ ZPKp, const short* __restrict__ WTp1,
    const float* __restrict__ bp1, short* __restrict__ APK)
{
    __shared__ f32x4 red[2][16][64];
    const int bid = blockIdx.x;
    const bool pathA = bid < GBLKS;
    const int b = pathA ? bid : bid - GBLKS;
    const short* Apk = pathA ? ZPKr : ZPKp;
    const short* Wpk = pathA ? WT2 : WTp1;
    const float* bias = pathA ? b2 : bp1;

    f32x4 acc[4][4];
    int rowblk, colblk;
    bool epi = gemm_splitk_core(Apk, Wpk, b, acc, red, rowblk, colblk);
    if (!epi) return;
    if (pathA) epi_bf16(acc, bias, Hb, rowblk, colblk);
    else       epi_pack(acc, bias, APK, rowblk, colblk);
}

// ================= fused GEMM4 || aggregate2 =================
// blocks [0,GBLKS): APK@WTp2+bp2 -> proj (f32); [GBLKS,GBLKS+N_NODES): aggregate -> out

__global__ __launch_bounds__(256) void gemm4_agg2_kernel(
    const short* __restrict__ APK, const short* __restrict__ WTp2,
    const float* __restrict__ bp2, float* __restrict__ proj,
    const unsigned short* __restrict__ Hb,
    const float* __restrict__ dis,
    const int* __restrict__ row_off,
    const int* __restrict__ csr_src,
    const float* __restrict__ csr_norm,
    float* __restrict__ out)
{
    __shared__ f32x4 red[2][16][64];
    const int bid = blockIdx.x;
    if (bid < GBLKS) {
        f32x4 acc[4][4];
        int rowblk, colblk;
        if (gemm_splitk_core(APK, WTp2, bid, acc, red, rowblk, colblk))
            epi_f32(acc, bp2, proj, rowblk, colblk);
        return;
    }
    const int node = bid - GBLKS;
    const int t = threadIdx.x;
    const int start = row_off[node];
    const int end   = row_off[node + 1];
    const float dn = dis[node];
    const float sw = dn * dn;

    ushort2 hv = *((const ushort2*)(Hb + (size_t)node * DIM) + t);
    float a0 = bf16_to_f32(hv.x) * sw;
    float a1 = bf16_to_f32(hv.y) * sw;

    int e = start;
    for (; e + 3 < end; e += 4) {
        int s0 = csr_src[e],     s1 = csr_src[e + 1];
        int s2 = csr_src[e + 2], s3 = csr_src[e + 3];
        float w0 = csr_norm[e],     w1 = csr_norm[e + 1];
        float w2 = csr_norm[e + 2], w3 = csr_norm[e + 3];
        ushort2 v0 = *((const ushort2*)(Hb + (size_t)s0 * DIM) + t);
        ushort2 v1 = *((const ushort2*)(Hb + (size_t)s1 * DIM) + t);
        ushort2 v2 = *((const ushort2*)(Hb + (size_t)s2 * DIM) + t);
        ushort2 v3 = *((const ushort2*)(Hb + (size_t)s3 * DIM) + t);
        a0 += bf16_to_f32(v0.x) * w0 + bf16_to_f32(v1.x) * w1
            + bf16_to_f32(v2.x) * w2 + bf16_to_f32(v3.x) * w3;
        a1 += bf16_to_f32(v0.y) * w0 + bf16_to_f32(v1.y) * w1
            + bf16_to_f32(v2.y) * w2 + bf16_to_f32(v3.y) * w3;
    }
    for (; e < end; ++e) {
        int s = csr_src[e];
        float w = csr_norm[e];
        ushort2 v = *((const ushort2*)(Hb + (size_t)s * DIM) + t);
        a0 += bf16_to_f32(v.x) * w;
        a1 += bf16_to_f32(v.y) * w;
    }
    *((float2*)(out + (size_t)node * DIM) + t) = make_float2(a0, a1);
}

// ================= launch =================

extern "C" void kernel_launch(void* const* d_in, const int* in_sizes, int n_in,
                              void* d_out, int out_size, void* d_ws, size_t ws_size,
                              hipStream_t stream) {
    const float* x   = (const float*)d_in[0];
    const int*   ei  = (const int*)d_in[1];
    const float* W1  = (const float*)d_in[2];
    const float* b1  = (const float*)d_in[3];
    const float* W2  = (const float*)d_in[4];
    const float* b2  = (const float*)d_in[5];
    const float* Wp1 = (const float*)d_in[6];
    const float* bp1 = (const float*)d_in[7];
    const float* Wp2 = (const float*)d_in[8];
    const float* bp2 = (const float*)d_in[9];

    float* out  = (float*)d_out;
    float* z    = out + (size_t)N_NODES * DIM;
    float* proj = z   + (size_t)N_NODES * DIM;

    char* ws = (char*)d_ws;
    size_t off = 0;
    auto walloc = [&](size_t bytes) -> void* {
        void* p = ws + off;
        off = (off + bytes + 255) & ~(size_t)255;
        return p;
    };
    const size_t PK_SHORTS = (size_t)RBLKS * 16 * 4096;
    unsigned short* Hb = (unsigned short*)walloc((size_t)N_NODES * DIM * sizeof(unsigned short));
    short* APK0 = (short*)walloc(PK_SHORTS * sizeof(short));
    short* ZPKp = (short*)walloc(PK_SHORTS * sizeof(short));
    short* ZPKr = (short*)walloc(PK_SHORTS * sizeof(short));
    short* WT1  = (short*)walloc((size_t)8 * 16 * 4096 * sizeof(short));
    short* WT2  = (short*)walloc((size_t)8 * 16 * 4096 * sizeof(short));
    short* WTp1 = (short*)walloc((size_t)8 * 16 * 4096 * sizeof(short));
    short* WTp2 = (short*)walloc((size_t)8 * 16 * 4096 * sizeof(short));
    int*   deg      = (int*)  walloc(N_NODES * sizeof(int));
    int*   cursor   = (int*)  walloc(N_NODES * sizeof(int));
    int*   row_off  = (int*)  walloc((N_NODES + 1) * sizeof(int));
    int*   bsum     = (int*)  walloc(SCAN_BLKS * sizeof(int));
    float* dis      = (float*)walloc(N_NODES * sizeof(float));
    int*   csr_src  = (int*)  walloc(N_EDGES * sizeof(int));
    float* csr_norm = (float*)walloc(N_EDGES * sizeof(float));

    const dim3 blk(256);
    const dim3 wave(64);
    const int  EBLKS = (N_EDGES + 255) / 256;   // 625

    // 1: pack weights || zero deg
    packw_zero_kernel<<<dim3(512 + SCAN_BLKS), blk, 0, stream>>>(
        W1, W2, Wp1, Wp2, WT1, WT2, WTp1, WTp2, deg);
    // 2: pack x || count deg
    packa_count_kernel<<<dim3(2512 + EBLKS), blk, 0, stream>>>(x, APK0, ei, deg);
    // 3-5: scan
    scan1_kernel<<<dim3(SCAN_BLKS), blk, 0, stream>>>(deg, row_off, bsum, dis, cursor, N_NODES);
    scan2_kernel<<<dim3(1), wave, 0, stream>>>(bsum);
    scan3_kernel<<<dim3(SCAN_BLKS), blk, 0, stream>>>(row_off, bsum, N_NODES);
    // 6: GEMM1 || scatter
    gemm1_scatter_kernel<<<dim3(GBLKS + EBLKS), blk, 0, stream>>>(
        APK0, WT1, b1, Hb, ei, dis, row_off, cursor, csr_src, csr_norm);
    // 7: aggregate1 + fused z-pack
    agg1_pack_kernel<<<dim3(N_NODES), blk, 0, stream>>>(
        Hb, dis, row_off, csr_src, csr_norm, z, ZPKp, ZPKr);
    // 8: GEMM2 || GEMM3
    gemm23_kernel<<<dim3(2 * GBLKS), blk, 0, stream>>>(
        ZPKr, WT2, b2, Hb, ZPKp, WTp1, bp1, APK0);
    // 9: GEMM4 || aggregate2
    gemm4_agg2_kernel<<<dim3(GBLKS + N_NODES), blk, 0, stream>>>(
        APK0, WTp2, bp2, proj, Hb, dis, row_off, csr_src, csr_norm, out);
}